// Round 2
// baseline (700.408 us; speedup 1.0000x reference)
//
#include <hip/hip_runtime.h>
#include <hip/hip_bf16.h>

typedef __hip_bfloat16 bf16;
typedef __attribute__((ext_vector_type(8))) short short8;
typedef __attribute__((ext_vector_type(4))) float floatx4;

#define L_SZ 8192
#define FFT_M 8192      // complex FFT size (packed real 16384)
#define HFS 8200        // hf row stride in float2 (8193 used)

__device__ __forceinline__ float b2f(bf16 x) { return __bfloat162float(x); }
__device__ __forceinline__ bf16 f2b(float x) { return __float2bfloat16(x); }
__device__ __forceinline__ short f2bs(float x) {
    bf16 b = __float2bfloat16(x);
    return *reinterpret_cast<short*>(&b);
}
__device__ __forceinline__ short8 pack8(float4 a, float4 b) {
    short8 r;
    r[0] = f2bs(a.x); r[1] = f2bs(a.y); r[2] = f2bs(a.z); r[3] = f2bs(a.w);
    r[4] = f2bs(b.x); r[5] = f2bs(b.y); r[6] = f2bs(b.z); r[7] = f2bs(b.w);
    return r;
}
__device__ __forceinline__ int rev13(int x) { return (int)(__brev((unsigned)x) >> 19); }

// ---------------------------------------------------------------------------
// GEMM A: proj[n, m] = sum_k in_W[n,k] * x[m,k] + in_b[n]
// n in [0,768) (W rows = MFMA A-operand), m = b*L+l in [0,65536) (x rows = B-op)
// fp32 global inputs, converted to bf16 while staging into LDS.
// epilogue scatters: n<256 -> v fp32 [b][d][l]; 256..511 -> raw0 bf16; else raw1
// ---------------------------------------------------------------------------
__global__ __launch_bounds__(256) void gemm_proj(
    const float* __restrict__ x, const float* __restrict__ inW, const float* __restrict__ inb,
    float* __restrict__ v, bf16* __restrict__ raw0, bf16* __restrict__ raw1)
{
    __shared__ __align__(16) short sW[64 * 72];
    __shared__ __align__(16) short sX[256 * 72];
    const int tid = threadIdx.x;
    const int wave = tid >> 6, lane = tid & 63, quad = lane >> 4, l16 = lane & 15;
    const int bm = blockIdx.x * 256;
    const int bn = blockIdx.y * 64;

    floatx4 acc[4][4];
#pragma unroll
    for (int i = 0; i < 4; ++i)
#pragma unroll
        for (int j = 0; j < 4; ++j) acc[i][j] = (floatx4){0.f, 0.f, 0.f, 0.f};

    const int r0 = tid >> 3, c0 = (tid & 7) * 8;
    for (int s = 0; s < 4; ++s) {
        const int koff = s * 64;
        short8 wreg[2], xreg[8];
#pragma unroll
        for (int j = 0; j < 2; ++j) {
            const float* p = inW + (size_t)(bn + j * 32 + r0) * 256 + koff + c0;
            wreg[j] = pack8(*(const float4*)p, *(const float4*)(p + 4));
        }
#pragma unroll
        for (int j = 0; j < 8; ++j) {
            const float* p = x + (size_t)(bm + j * 32 + r0) * 256 + koff + c0;
            xreg[j] = pack8(*(const float4*)p, *(const float4*)(p + 4));
        }
        __syncthreads();
#pragma unroll
        for (int j = 0; j < 2; ++j)
            *(short8*)(&sW[(j * 32 + r0) * 72 + c0]) = wreg[j];
#pragma unroll
        for (int j = 0; j < 8; ++j)
            *(short8*)(&sX[(j * 32 + r0) * 72 + c0]) = xreg[j];
        __syncthreads();
#pragma unroll
        for (int kk = 0; kk < 64; kk += 32) {
            const int ko = kk + quad * 8;
            short8 wf[4], xf[4];
#pragma unroll
            for (int ts = 0; ts < 4; ++ts)
                wf[ts] = *(const short8*)(&sW[(ts * 16 + l16) * 72 + ko]);
#pragma unroll
            for (int tb = 0; tb < 4; ++tb)
                xf[tb] = *(const short8*)(&sX[(wave * 64 + tb * 16 + l16) * 72 + ko]);
#pragma unroll
            for (int ts = 0; ts < 4; ++ts)
#pragma unroll
                for (int tb = 0; tb < 4; ++tb)
                    acc[ts][tb] = __builtin_amdgcn_mfma_f32_16x16x32_bf16(
                        wf[ts], xf[tb], acc[ts][tb], 0, 0, 0);
        }
    }
    const int seg = bn >> 8;
#pragma unroll
    for (int ts = 0; ts < 4; ++ts) {
#pragma unroll
        for (int r = 0; r < 4; ++r) {
            const int nglob = bn + ts * 16 + quad * 4 + r;   // D row = A-op index
            const float bias = inb[nglob];
            const int c = nglob & 255;
#pragma unroll
            for (int tb = 0; tb < 4; ++tb) {
                const int m = bm + wave * 64 + tb * 16 + l16; // D col = B-op index
                const int bb = m >> 13, l = m & 8191;
                const size_t idx = ((size_t)(bb * 256 + c)) * 8192 + l;
                const float val = acc[ts][tb][r] + bias;
                if (seg == 0) v[idx] = val;
                else if (seg == 1) raw0[idx] = f2b(val);
                else raw1[idx] = f2b(val);
            }
        }
    }
}

// ---------------------------------------------------------------------------
// GEMM F: out[m, n] = sum_k gated[m,k] * out_W[n,k] + out_b[n]
// gated is bf16 (produced by gate_transpose); out_W fp32 -> bf16 staging.
// ---------------------------------------------------------------------------
__global__ __launch_bounds__(256) void gemm_out_k(
    const bf16* __restrict__ gated, const float* __restrict__ outW, const float* __restrict__ outb,
    float* __restrict__ out)
{
    __shared__ __align__(16) short sW[64 * 72];
    __shared__ __align__(16) short sA[256 * 72];
    const int tid = threadIdx.x;
    const int wave = tid >> 6, lane = tid & 63, quad = lane >> 4, l16 = lane & 15;
    const int bm = blockIdx.x * 256;
    const int bn = blockIdx.y * 64;

    floatx4 acc[4][4]; // [tb(m)][ts(n)]
#pragma unroll
    for (int i = 0; i < 4; ++i)
#pragma unroll
        for (int j = 0; j < 4; ++j) acc[i][j] = (floatx4){0.f, 0.f, 0.f, 0.f};

    const int r0 = tid >> 3, c0 = (tid & 7) * 8;
    for (int s = 0; s < 4; ++s) {
        const int koff = s * 64;
        short8 wreg[2];
        uint4 areg[8];
#pragma unroll
        for (int j = 0; j < 2; ++j) {
            const float* p = outW + (size_t)(bn + j * 32 + r0) * 256 + koff + c0;
            wreg[j] = pack8(*(const float4*)p, *(const float4*)(p + 4));
        }
#pragma unroll
        for (int j = 0; j < 8; ++j)
            areg[j] = *(const uint4*)(gated + (size_t)(bm + j * 32 + r0) * 256 + koff + c0);
        __syncthreads();
#pragma unroll
        for (int j = 0; j < 2; ++j)
            *(short8*)(&sW[(j * 32 + r0) * 72 + c0]) = wreg[j];
#pragma unroll
        for (int j = 0; j < 8; ++j)
            *(uint4*)(&sA[(j * 32 + r0) * 72 + c0]) = areg[j];
        __syncthreads();
#pragma unroll
        for (int kk = 0; kk < 64; kk += 32) {
            const int ko = kk + quad * 8;
            short8 bfr[4], af[4];
#pragma unroll
            for (int ts = 0; ts < 4; ++ts)
                bfr[ts] = *(const short8*)(&sW[(ts * 16 + l16) * 72 + ko]);
#pragma unroll
            for (int tb = 0; tb < 4; ++tb)
                af[tb] = *(const short8*)(&sA[(wave * 64 + tb * 16 + l16) * 72 + ko]);
#pragma unroll
            for (int tb = 0; tb < 4; ++tb)
#pragma unroll
                for (int ts = 0; ts < 4; ++ts)
                    acc[tb][ts] = __builtin_amdgcn_mfma_f32_16x16x32_bf16(
                        af[tb], bfr[ts], acc[tb][ts], 0, 0, 0);
        }
    }
#pragma unroll
    for (int tb = 0; tb < 4; ++tb) {
#pragma unroll
        for (int r = 0; r < 4; ++r) {
            const int m = bm + wave * 64 + tb * 16 + quad * 4 + r;
#pragma unroll
            for (int ts = 0; ts < 4; ++ts) {
                const int n = bn + ts * 16 + l16;
                out[(size_t)m * 256 + n] = acc[tb][ts][r] + outb[n];
            }
        }
    }
}

// ---------------------------------------------------------------------------
// h[d, l] = silu(t_l*W1 + b1) @ W2[d,:] + b2[d]   (all fp32)
// ---------------------------------------------------------------------------
__global__ __launch_bounds__(256) void build_h(
    const float* __restrict__ tpos, const float* __restrict__ W1, const float* __restrict__ b1,
    const float* __restrict__ W2, const float* __restrict__ b2, float* __restrict__ h)
{
    __shared__ float s[32][64];
    __shared__ float tr[256 * 32];
    const int tid = threadIdx.x;
    const int l0 = blockIdx.x * 32;
#pragma unroll
    for (int p = 0; p < 8; ++p) {
        int idx = tid + p * 256;
        int li = idx >> 6, j = idx & 63;
        float tv = tpos[l0 + li];
        float z = tv * W1[j] + b1[j];
        s[li][j] = z / (1.f + __expf(-z));
    }
    __syncthreads();
    const int d = tid;
    float acc[32];
    float bb = b2[d];
#pragma unroll
    for (int li = 0; li < 32; ++li) acc[li] = bb;
    for (int j = 0; j < 64; ++j) {
        float w = W2[d * 64 + j];
#pragma unroll
        for (int li = 0; li < 32; ++li) acc[li] += w * s[li][j];
    }
#pragma unroll
    for (int li = 0; li < 32; ++li) tr[d * 32 + li] = acc[li];
    __syncthreads();
#pragma unroll
    for (int p = 0; p < 8; ++p) {
        int idx = tid + p * 256;
        int row = idx >> 3, c = (idx & 7) * 4;
        *(float4*)(h + (size_t)row * 8192 + l0 + c) = *(const float4*)(&tr[row * 32 + c]);
    }
}

// ---------------------------------------------------------------------------
// radix-2 complex FFT-8192, 1024 threads. DIF: natural in -> bitrev out.
// DIT inverse (W^+): bitrev in -> natural out (unnormalized).
// ---------------------------------------------------------------------------
__device__ __forceinline__ void fft8192_dif(float* re, float* im, int tid)
{
    for (int lm = 13; lm >= 1; --lm) {
        const int m = 1 << lm, half = m >> 1;
        const float cst = -6.28318530718f / (float)m;
#pragma unroll 4
        for (int j = 0; j < 4; ++j) {
            const int i = tid + j * 1024;
            const int k = i & (half - 1);
            const int i1 = ((i >> (lm - 1)) << lm) | k;
            const int i2 = i1 + half;
            float ur = re[i1], ui = im[i1], vr = re[i2], vi = im[i2];
            float dr = ur - vr, di = ui - vi;
            re[i1] = ur + vr; im[i1] = ui + vi;
            float sn, cs;
            __sincosf(cst * (float)k, &sn, &cs);
            re[i2] = dr * cs - di * sn;
            im[i2] = dr * sn + di * cs;
        }
        __syncthreads();
    }
}

__device__ __forceinline__ void fft8192_dit_inv(float* re, float* im, int tid)
{
    for (int lm = 1; lm <= 13; ++lm) {
        const int m = 1 << lm, half = m >> 1;
        const float cst = 6.28318530718f / (float)m;
#pragma unroll 4
        for (int j = 0; j < 4; ++j) {
            const int i = tid + j * 1024;
            const int k = i & (half - 1);
            const int i1 = ((i >> (lm - 1)) << lm) | k;
            const int i2 = i1 + half;
            float tr_ = re[i2], ti = im[i2];
            float sn, cs;
            __sincosf(cst * (float)k, &sn, &cs);
            float wr = tr_ * cs - ti * sn;
            float wi = tr_ * sn + ti * cs;
            float ur = re[i1], ui = im[i1];
            re[i1] = ur + wr; im[i1] = ui + wi;
            re[i2] = ur - wr; im[i2] = ui - wi;
        }
        __syncthreads();
    }
}

#define ANGN 3.83495197e-4f   // 2*pi/16384

// hf[d][k] = rfft_16384(h[d])[k], k = 0..8192 (natural order)
__global__ __launch_bounds__(1024) void fft_filter(
    const float* __restrict__ h, float2* __restrict__ hf)
{
    __shared__ float re[FFT_M];
    __shared__ float im[FFT_M];
    const int d = blockIdx.x;
    const int tid = threadIdx.x;
    const float2* hrow = (const float2*)(h + (size_t)d * L_SZ);
    for (int n = tid; n < 4096; n += 1024) { float2 z = hrow[n]; re[n] = z.x; im[n] = z.y; }
    for (int n = tid + 4096; n < 8192; n += 1024) { re[n] = 0.f; im[n] = 0.f; }
    __syncthreads();
    fft8192_dif(re, im, tid);
    float2* outp = hf + (size_t)d * HFS;
    for (int k = tid; k < 8193; k += 1024) {
        const int ka = k & 8191;
        const int kb = (8192 - k) & 8191;
        const int p1 = rev13(ka), p2 = rev13(kb);
        float zr = re[p1], zi = im[p1], wr2 = re[p2], wi2 = im[p2];
        float xer = 0.5f * (zr + wr2), xei = 0.5f * (zi - wi2);
        float xor_ = 0.5f * (zi + wi2), xoi = 0.5f * (wr2 - zr);
        float sn, cs;
        __sincosf(-ANGN * (float)k, &sn, &cs);
        float2 o;
        o.x = xer + (xor_ * cs - xoi * sn);
        o.y = xei + (xor_ * sn + xoi * cs);
        outp[k] = o;
    }
}

// per (b,d) row: y = irfft(rfft(v_pad) * hf[d])[:8192], in-place over v
__global__ __launch_bounds__(1024) void fft_conv(
    float* __restrict__ vy, const float2* __restrict__ hf)
{
    __shared__ float re[FFT_M];
    __shared__ float im[FFT_M];
    const int bid = blockIdx.x;
    const int d = bid >> 3, b = bid & 7;
    const int tid = threadIdx.x;
    float* row = vy + ((size_t)(b * 256 + d)) * L_SZ;
    const float2* row2c = (const float2*)row;
    for (int n = tid; n < 4096; n += 1024) { float2 z = row2c[n]; re[n] = z.x; im[n] = z.y; }
    for (int n = tid + 4096; n < 8192; n += 1024) { re[n] = 0.f; im[n] = 0.f; }
    __syncthreads();
    fft8192_dif(re, im, tid);
    const float2* H = hf + (size_t)d * HFS;
    if (tid == 0) {
        // k = 0 / k = M pair (both spectra real there)
        float z0r = re[0], z0i = im[0];
        float x0 = z0r + z0i, xm = z0r - z0i;
        float2 h0 = H[0], hm = H[8192];
        float y0r = x0 * h0.x, y0i = x0 * h0.y;
        float ymr = xm * hm.x, ymi = xm * hm.y;
        float yer = 0.5f * (y0r + ymr), yei = 0.5f * (y0i + ymi);
        float yor = 0.5f * (y0r - ymr), yoi = 0.5f * (y0i - ymi);
        re[0] = yer - yoi;
        im[0] = yei + yor;
    }
#pragma unroll 4
    for (int j = 0; j < 4; ++j) {
        const int k = 1 + tid + j * 1024;          // k in [1, 4096]
        const int mk = 8192 - k;
        const int p1 = rev13(k), p2 = rev13(mk);
        float zr = re[p1], zi = im[p1], z2r = re[p2], z2i = im[p2];
        // untangle: X[k] = Xe + W*Xo ; X[mk] = conj(Xe - W*Xo)
        float xer = 0.5f * (zr + z2r), xei = 0.5f * (zi - z2i);
        float xor_ = 0.5f * (zi + z2i), xoi = 0.5f * (z2r - zr);
        float sn, cs;
        __sincosf(-ANGN * (float)k, &sn, &cs);     // W = (cs, sn)
        float pr = xor_ * cs - xoi * sn, pi = xor_ * sn + xoi * cs;
        float xkr = xer + pr, xki = xei + pi;
        float xmr = xer - pr, xmi = pi - xei;
        // multiply with filter spectrum
        float2 hk = H[k], hm = H[mk];
        float ykr = xkr * hk.x - xki * hk.y, yki = xkr * hk.y + xki * hk.x;
        float ymr = xmr * hm.x - xmi * hm.y, ymi = xmr * hm.y + xmi * hm.x;
        // retangle: z'[k] = Ye + i*Yo, Yo = conj(W)*Dm
        float yer = 0.5f * (ykr + ymr), yei = 0.5f * (yki - ymi);
        float dmr = 0.5f * (ykr - ymr), dmi = 0.5f * (yki + ymi);
        float yor = dmr * cs + dmi * sn;
        float yoi = dmi * cs - dmr * sn;
        re[p1] = yer - yoi;
        im[p1] = yei + yor;
        re[p2] = yer + yoi;
        im[p2] = yor - yei;
    }
    __syncthreads();
    fft8192_dit_inv(re, im, tid);
    const float sc = 1.0f / 8192.0f;
    float2* row2 = (float2*)row;
    for (int n = tid; n < 4096; n += 1024) {
        float2 o; o.x = re[n] * sc; o.y = im[n] * sc;
        row2[n] = o;
    }
}

// ---------------------------------------------------------------------------
// gated[b][l][d] = y[b][d][l] * dwconv3(raw0)[b][d][l] * dwconv3(raw1)[b][d][l]
// (LDS 64x64 transpose for coalesced [b,l,d] bf16 output)
// ---------------------------------------------------------------------------
__global__ __launch_bounds__(256) void gate_transpose(
    const float* __restrict__ y, const bf16* __restrict__ raw0, const bf16* __restrict__ raw1,
    const float* __restrict__ cw0, const float* __restrict__ cb0,
    const float* __restrict__ cw1, const float* __restrict__ cb1,
    bf16* __restrict__ gated)
{
    __shared__ float T[64][65];
    const int tid = threadIdx.x;
    const int r = tid >> 6, ln = tid & 63;
    const int b = blockIdx.z, l0 = blockIdx.x * 64, d0 = blockIdx.y * 64;
    const int l = l0 + ln;
#pragma unroll
    for (int rr = 0; rr < 16; ++rr) {
        const int d = d0 + rr * 4 + r;
        const size_t base = ((size_t)(b * 256 + d)) * L_SZ + l;
        const float yv = y[base];
        const float r0m = (l > 0) ? b2f(raw0[base - 1]) : 0.f;
        const float r0c = b2f(raw0[base]);
        const float r0p = (l < 8191) ? b2f(raw0[base + 1]) : 0.f;
        const float r1m = (l > 0) ? b2f(raw1[base - 1]) : 0.f;
        const float r1c = b2f(raw1[base]);
        const float r1p = (l < 8191) ? b2f(raw1[base + 1]) : 0.f;
        const float g0 = cw0[d * 3] * r0m + cw0[d * 3 + 1] * r0c
                       + cw0[d * 3 + 2] * r0p + cb0[d];
        const float g1 = cw1[d * 3] * r1m + cw1[d * 3 + 1] * r1c
                       + cw1[d * 3 + 2] * r1p + cb1[d];
        T[ln][rr * 4 + r] = yv * g0 * g1;
    }
    __syncthreads();
#pragma unroll
    for (int p = 0; p < 16; ++p) {
        const int i = p * 4 + r;
        gated[((size_t)(b * L_SZ) + l0 + i) * 256 + d0 + ln] = f2b(T[i][ln]);
    }
}

// ---------------------------------------------------------------------------
extern "C" void kernel_launch(void* const* d_in, const int* in_sizes, int n_in,
                              void* d_out, int out_size, void* d_ws, size_t ws_size,
                              hipStream_t stream)
{
    const float* x    = (const float*)d_in[0];
    const float* inW  = (const float*)d_in[1];
    const float* inb  = (const float*)d_in[2];
    const float* c0W  = (const float*)d_in[3];
    const float* c0b  = (const float*)d_in[4];
    const float* c1W  = (const float*)d_in[5];
    const float* c1b  = (const float*)d_in[6];
    const float* mW1  = (const float*)d_in[7];
    const float* mb1  = (const float*)d_in[8];
    const float* mW2  = (const float*)d_in[9];
    const float* mb2  = (const float*)d_in[10];
    const float* oW   = (const float*)d_in[11];
    const float* ob   = (const float*)d_in[12];
    const float* tpos = (const float*)d_in[13];
    float* out = (float*)d_out;

    char* ws = (char*)d_ws;
    float*  v     = (float*)(ws);                   // 67,108,864 B  [B][D][L] fp32 (y in-place)
    bf16*   raw0  = (bf16*)(ws + 67108864);         // 33,554,432 B
    bf16*   raw1  = (bf16*)(ws + 100663296);        // 33,554,432 B
    float*  h     = (float*)(ws + 134217728);       //  8,388,608 B  [D][L]
    float2* hf    = (float2*)(ws + 142606336);      // 16,793,600 B  [D][HFS]
    bf16*   gated = (bf16*)(ws + 159399936);        // 33,554,432 B  [B][L][D]

    gemm_proj<<<dim3(256, 12), 256, 0, stream>>>(x, inW, inb, v, raw0, raw1);
    build_h<<<256, 256, 0, stream>>>(tpos, mW1, mb1, mW2, mb2, h);
    fft_filter<<<256, 1024, 0, stream>>>(h, hf);
    fft_conv<<<2048, 1024, 0, stream>>>(v, hf);
    gate_transpose<<<dim3(128, 4, 8), 256, 0, stream>>>(v, raw0, raw1, c0W, c0b, c1W, c1b, gated);
    gemm_out_k<<<dim3(256, 4), 256, 0, stream>>>(gated, oW, ob, out);
}

// Round 3
// 578.608 us; speedup vs baseline: 1.2105x; 1.2105x over previous
//
#include <hip/hip_runtime.h>
#include <hip/hip_bf16.h>

typedef __hip_bfloat16 bf16;
typedef __attribute__((ext_vector_type(8))) short short8;
typedef __attribute__((ext_vector_type(4))) float floatx4;

#define L_SZ 8192
#define HFS 8193        // hf row stride in float2
#define PD(i) ((i) + ((i) >> 4))   // LDS pad: bank-spread for all FFT strides

__device__ __forceinline__ float b2f(bf16 x) { return __bfloat162float(x); }
__device__ __forceinline__ bf16 f2b(float x) { return __float2bfloat16(x); }
__device__ __forceinline__ short f2bs(float x) {
    bf16 b = __float2bfloat16(x);
    return *reinterpret_cast<short*>(&b);
}
__device__ __forceinline__ short8 pack8(float4 a, float4 b) {
    short8 r;
    r[0] = f2bs(a.x); r[1] = f2bs(a.y); r[2] = f2bs(a.z); r[3] = f2bs(a.w);
    r[4] = f2bs(b.x); r[5] = f2bs(b.y); r[6] = f2bs(b.z); r[7] = f2bs(b.w);
    return r;
}

// storage position of frequency k after DIF stages radix [8,8,8,8,2]
__device__ __forceinline__ int permP(int k) {
    return ((k & 7) << 10) | (((k >> 3) & 7) << 7) | (((k >> 6) & 7) << 4)
         | (((k >> 9) & 7) << 1) | ((k >> 12) & 1);
}

// ---------------------------------------------------------------------------
// 8-point DFT, SF=-1 forward (w8=e^{-2pi i/8}), SF=+1 inverse
// ---------------------------------------------------------------------------
template<int SF>
__device__ __forceinline__ void dft8(const float xr[8], const float xi[8],
                                     float yr[8], float yi[8]) {
    constexpr float sgn = (SF < 0) ? -1.f : 1.f;
    const float S2 = 0.70710678118654752f;
    float t0r=xr[0]+xr[4], t0i=xi[0]+xi[4];
    float t1r=xr[0]-xr[4], t1i=xi[0]-xi[4];
    float t2r=xr[2]+xr[6], t2i=xi[2]+xi[6];
    float t3r=xr[2]-xr[6], t3i=xi[2]-xi[6];
    float u0r=xr[1]+xr[5], u0i=xi[1]+xi[5];
    float u1r=xr[1]-xr[5], u1i=xi[1]-xi[5];
    float u2r=xr[3]+xr[7], u2i=xi[3]+xi[7];
    float u3r=xr[3]-xr[7], u3i=xi[3]-xi[7];
    float m3r = -sgn*t3i, m3i = sgn*t3r;           // (sgn*i)*t3
    float n3r = -sgn*u3i, n3i = sgn*u3r;
    float E0r=t0r+t2r, E0i=t0i+t2i, E2r=t0r-t2r, E2i=t0i-t2i;
    float E1r=t1r+m3r, E1i=t1i+m3i, E3r=t1r-m3r, E3i=t1i-m3i;
    float O0r=u0r+u2r, O0i=u0i+u2i, O2r=u0r-u2r, O2i=u0i-u2i;
    float O1r=u1r+n3r, O1i=u1i+n3i, O3r=u1r-n3r, O3i=u1i-n3i;
    float a1r = S2*(O1r - sgn*O1i),  a1i = S2*(O1i + sgn*O1r);   // w8^1*O1
    float a2r = -sgn*O2i,            a2i = sgn*O2r;              // w8^2*O2
    float a3r = S2*(-O3r - sgn*O3i), a3i = S2*(sgn*O3r - O3i);   // w8^3*O3
    yr[0]=E0r+O0r; yi[0]=E0i+O0i; yr[4]=E0r-O0r; yi[4]=E0i-O0i;
    yr[1]=E1r+a1r; yi[1]=E1i+a1i; yr[5]=E1r-a1r; yi[5]=E1i-a1i;
    yr[2]=E2r+a2r; yi[2]=E2i+a2i; yr[6]=E2r-a2r; yi[6]=E2i-a2i;
    yr[3]=E3r+a3r; yi[3]=E3i+a3i; yr[7]=E3r-a3r; yi[7]=E3i-a3i;
}

// radix-8 DIF stage (forward): DFT8 then twiddle W_M^{k*j'}
template<int M>
__device__ __forceinline__ void stage8_fwd(float* re, float* im, int t) {
    constexpr int ST = M / 8;
    const int k = t & (ST - 1);
    const int i1 = ((t & ~(ST - 1)) << 3) | k;
    float xr[8], xi[8];
#pragma unroll
    for (int j = 0; j < 8; ++j) { int a = PD(i1 + j * ST); xr[j] = re[a]; xi[j] = im[a]; }
    float yr[8], yi[8];
    dft8<-1>(xr, xi, yr, yi);
    float c1, s1;
    __sincosf(-6.283185307179586f * (float)k / (float)M, &s1, &c1);
    float wr = c1, wi = s1;
#pragma unroll
    for (int jp = 1; jp < 8; ++jp) {
        float a = yr[jp], b = yi[jp];
        yr[jp] = a * wr - b * wi;
        yi[jp] = a * wi + b * wr;
        float nr = wr * c1 - wi * s1, ni = wr * s1 + wi * c1;
        wr = nr; wi = ni;
    }
#pragma unroll
    for (int j = 0; j < 8; ++j) { int a = PD(i1 + j * ST); re[a] = yr[j]; im[a] = yi[j]; }
}

// radix-8 DIT stage (inverse): twiddle conj(W_M)^{k*j} then inverse DFT8
template<int M>
__device__ __forceinline__ void stage8_inv(float* re, float* im, int t) {
    constexpr int ST = M / 8;
    const int k = t & (ST - 1);
    const int i1 = ((t & ~(ST - 1)) << 3) | k;
    float xr[8], xi[8];
#pragma unroll
    for (int j = 0; j < 8; ++j) { int a = PD(i1 + j * ST); xr[j] = re[a]; xi[j] = im[a]; }
    float c1, s1;
    __sincosf(6.283185307179586f * (float)k / (float)M, &s1, &c1);
    float wr = c1, wi = s1;
#pragma unroll
    for (int j = 1; j < 8; ++j) {
        float a = xr[j], b = xi[j];
        xr[j] = a * wr - b * wi;
        xi[j] = a * wi + b * wr;
        float nr = wr * c1 - wi * s1, ni = wr * s1 + wi * c1;
        wr = nr; wi = ni;
    }
    float yr[8], yi[8];
    dft8<1>(xr, xi, yr, yi);
#pragma unroll
    for (int j = 0; j < 8; ++j) { int a = PD(i1 + j * ST); re[a] = yr[j]; im[a] = yi[j]; }
}

// final/first radix-2 stage (m=2, no twiddle); 4 pairs per thread
__device__ __forceinline__ void stage2(float* re, float* im, int t) {
#pragma unroll
    for (int j = 0; j < 4; ++j) {
        const int i = t + j * 1024;
        const int a = PD(2 * i), b = PD(2 * i + 1);
        float ur = re[a], ui = im[a], vr = re[b], vi = im[b];
        re[a] = ur + vr; im[a] = ui + vi;
        re[b] = ur - vr; im[b] = ui - vi;
    }
}

__device__ __forceinline__ void fft_fwd(float* re, float* im, int t) {
    stage8_fwd<8192>(re, im, t); __syncthreads();
    stage8_fwd<1024>(re, im, t); __syncthreads();
    stage8_fwd<128>(re, im, t);  __syncthreads();
    stage8_fwd<16>(re, im, t);   __syncthreads();
    stage2(re, im, t);           __syncthreads();
}
__device__ __forceinline__ void fft_inv(float* re, float* im, int t) {
    stage2(re, im, t);           __syncthreads();
    stage8_inv<16>(re, im, t);   __syncthreads();
    stage8_inv<128>(re, im, t);  __syncthreads();
    stage8_inv<1024>(re, im, t); __syncthreads();
    stage8_inv<8192>(re, im, t); __syncthreads();
}

#define ANGN 3.83495197e-4f   // 2*pi/16384

// ---------------------------------------------------------------------------
// prep: fp32 -> bf16 casts of x, in_W, out_W
// ---------------------------------------------------------------------------
__global__ __launch_bounds__(256) void prep_cast(
    const float* __restrict__ x, const float* __restrict__ inW, const float* __restrict__ outW,
    bf16* __restrict__ xb, bf16* __restrict__ inWb, bf16* __restrict__ outWb)
{
    const int gid = blockIdx.x * 256 + threadIdx.x;   // 8320*256 = 2,129,920 units of 8
    const float* src; bf16* dst; size_t off;
    if (gid < 2097152)      { src = x;    dst = xb;    off = (size_t)gid; }
    else if (gid < 2121728) { src = inW;  dst = inWb;  off = (size_t)(gid - 2097152); }
    else                    { src = outW; dst = outWb; off = (size_t)(gid - 2121728); }
    const float4 a = *(const float4*)(src + off * 8);
    const float4 b = *(const float4*)(src + off * 8 + 4);
    *(short8*)(dst + off * 8) = pack8(a, b);
}

// ---------------------------------------------------------------------------
// GEMM A: proj[n, m] = sum_k in_W[n,k] * x[m,k] + in_b[n]   (bf16 inputs)
// grid (12 bn, 256 bm): bn fastest so same-x blocks are temporally adjacent
// ---------------------------------------------------------------------------
__global__ __launch_bounds__(256) void gemm_proj(
    const bf16* __restrict__ x, const bf16* __restrict__ inW, const float* __restrict__ inb,
    float* __restrict__ v, bf16* __restrict__ raw0, bf16* __restrict__ raw1)
{
    __shared__ __align__(16) short sW[64 * 72];
    __shared__ __align__(16) short sX[256 * 72];
    const int tid = threadIdx.x;
    const int wave = tid >> 6, lane = tid & 63, quad = lane >> 4, l16 = lane & 15;
    const int bn = blockIdx.x * 64;
    const int bm = blockIdx.y * 256;

    floatx4 acc[4][4];
#pragma unroll
    for (int i = 0; i < 4; ++i)
#pragma unroll
        for (int j = 0; j < 4; ++j) acc[i][j] = (floatx4){0.f, 0.f, 0.f, 0.f};

    const int r0 = tid >> 3, c0 = (tid & 7) * 8;
    for (int s = 0; s < 4; ++s) {
        const int koff = s * 64;
        uint4 wreg[2], xreg[8];
#pragma unroll
        for (int j = 0; j < 2; ++j)
            wreg[j] = *(const uint4*)(inW + (size_t)(bn + j * 32 + r0) * 256 + koff + c0);
#pragma unroll
        for (int j = 0; j < 8; ++j)
            xreg[j] = *(const uint4*)(x + (size_t)(bm + j * 32 + r0) * 256 + koff + c0);
        __syncthreads();
#pragma unroll
        for (int j = 0; j < 2; ++j)
            *(uint4*)(&sW[(j * 32 + r0) * 72 + c0]) = wreg[j];
#pragma unroll
        for (int j = 0; j < 8; ++j)
            *(uint4*)(&sX[(j * 32 + r0) * 72 + c0]) = xreg[j];
        __syncthreads();
#pragma unroll
        for (int kk = 0; kk < 64; kk += 32) {
            const int ko = kk + quad * 8;
            short8 wf[4], xf[4];
#pragma unroll
            for (int ts = 0; ts < 4; ++ts)
                wf[ts] = *(const short8*)(&sW[(ts * 16 + l16) * 72 + ko]);
#pragma unroll
            for (int tb = 0; tb < 4; ++tb)
                xf[tb] = *(const short8*)(&sX[(wave * 64 + tb * 16 + l16) * 72 + ko]);
#pragma unroll
            for (int ts = 0; ts < 4; ++ts)
#pragma unroll
                for (int tb = 0; tb < 4; ++tb)
                    acc[ts][tb] = __builtin_amdgcn_mfma_f32_16x16x32_bf16(
                        wf[ts], xf[tb], acc[ts][tb], 0, 0, 0);
        }
    }
    const int seg = bn >> 8;
#pragma unroll
    for (int ts = 0; ts < 4; ++ts) {
#pragma unroll
        for (int r = 0; r < 4; ++r) {
            const int nglob = bn + ts * 16 + quad * 4 + r;
            const float bias = inb[nglob];
            const int c = nglob & 255;
#pragma unroll
            for (int tb = 0; tb < 4; ++tb) {
                const int m = bm + wave * 64 + tb * 16 + l16;
                const int bb = m >> 13, l = m & 8191;
                const size_t idx = ((size_t)(bb * 256 + c)) * 8192 + l;
                const float val = acc[ts][tb][r] + bias;
                if (seg == 0) v[idx] = val;
                else if (seg == 1) raw0[idx] = f2b(val);
                else raw1[idx] = f2b(val);
            }
        }
    }
}

// ---------------------------------------------------------------------------
// GEMM F: out[m, n] = sum_k gated[m,k] * out_W[n,k] + out_b[n]
// grid (4 bn, 256 bm)
// ---------------------------------------------------------------------------
__global__ __launch_bounds__(256) void gemm_out_k(
    const bf16* __restrict__ gated, const bf16* __restrict__ outW, const float* __restrict__ outb,
    float* __restrict__ out)
{
    __shared__ __align__(16) short sW[64 * 72];
    __shared__ __align__(16) short sA[256 * 72];
    const int tid = threadIdx.x;
    const int wave = tid >> 6, lane = tid & 63, quad = lane >> 4, l16 = lane & 15;
    const int bn = blockIdx.x * 64;
    const int bm = blockIdx.y * 256;

    floatx4 acc[4][4]; // [tb(m)][ts(n)]
#pragma unroll
    for (int i = 0; i < 4; ++i)
#pragma unroll
        for (int j = 0; j < 4; ++j) acc[i][j] = (floatx4){0.f, 0.f, 0.f, 0.f};

    const int r0 = tid >> 3, c0 = (tid & 7) * 8;
    for (int s = 0; s < 4; ++s) {
        const int koff = s * 64;
        uint4 wreg[2], areg[8];
#pragma unroll
        for (int j = 0; j < 2; ++j)
            wreg[j] = *(const uint4*)(outW + (size_t)(bn + j * 32 + r0) * 256 + koff + c0);
#pragma unroll
        for (int j = 0; j < 8; ++j)
            areg[j] = *(const uint4*)(gated + (size_t)(bm + j * 32 + r0) * 256 + koff + c0);
        __syncthreads();
#pragma unroll
        for (int j = 0; j < 2; ++j)
            *(uint4*)(&sW[(j * 32 + r0) * 72 + c0]) = wreg[j];
#pragma unroll
        for (int j = 0; j < 8; ++j)
            *(uint4*)(&sA[(j * 32 + r0) * 72 + c0]) = areg[j];
        __syncthreads();
#pragma unroll
        for (int kk = 0; kk < 64; kk += 32) {
            const int ko = kk + quad * 8;
            short8 bfr[4], af[4];
#pragma unroll
            for (int ts = 0; ts < 4; ++ts)
                bfr[ts] = *(const short8*)(&sW[(ts * 16 + l16) * 72 + ko]);
#pragma unroll
            for (int tb = 0; tb < 4; ++tb)
                af[tb] = *(const short8*)(&sA[(wave * 64 + tb * 16 + l16) * 72 + ko]);
#pragma unroll
            for (int tb = 0; tb < 4; ++tb)
#pragma unroll
                for (int ts = 0; ts < 4; ++ts)
                    acc[tb][ts] = __builtin_amdgcn_mfma_f32_16x16x32_bf16(
                        af[tb], bfr[ts], acc[tb][ts], 0, 0, 0);
        }
    }
#pragma unroll
    for (int tb = 0; tb < 4; ++tb) {
#pragma unroll
        for (int r = 0; r < 4; ++r) {
            const int m = bm + wave * 64 + tb * 16 + quad * 4 + r;
#pragma unroll
            for (int ts = 0; ts < 4; ++ts) {
                const int n = bn + ts * 16 + l16;
                out[(size_t)m * 256 + n] = acc[tb][ts][r] + outb[n];
            }
        }
    }
}

// ---------------------------------------------------------------------------
// h[d, l] = silu(t_l*W1 + b1) @ W2[d,:] + b2[d]   (all fp32)
// ---------------------------------------------------------------------------
__global__ __launch_bounds__(256) void build_h(
    const float* __restrict__ tpos, const float* __restrict__ W1, const float* __restrict__ b1,
    const float* __restrict__ W2, const float* __restrict__ b2, float* __restrict__ h)
{
    __shared__ float s[32][64];
    __shared__ float tr[256 * 32];
    const int tid = threadIdx.x;
    const int l0 = blockIdx.x * 32;
#pragma unroll
    for (int p = 0; p < 8; ++p) {
        int idx = tid + p * 256;
        int li = idx >> 6, j = idx & 63;
        float tv = tpos[l0 + li];
        float z = tv * W1[j] + b1[j];
        s[li][j] = z / (1.f + __expf(-z));
    }
    __syncthreads();
    const int d = tid;
    float acc[32];
    float bb = b2[d];
#pragma unroll
    for (int li = 0; li < 32; ++li) acc[li] = bb;
    for (int j = 0; j < 64; ++j) {
        float w = W2[d * 64 + j];
#pragma unroll
        for (int li = 0; li < 32; ++li) acc[li] += w * s[li][j];
    }
#pragma unroll
    for (int li = 0; li < 32; ++li) tr[d * 32 + li] = acc[li];
    __syncthreads();
#pragma unroll
    for (int p = 0; p < 8; ++p) {
        int idx = tid + p * 256;
        int row = idx >> 3, c = (idx & 7) * 4;
        *(float4*)(h + (size_t)row * 8192 + l0 + c) = *(const float4*)(&tr[row * 32 + c]);
    }
}

// ---------------------------------------------------------------------------
// hf[d][k] = rfft_16384(h[d])[k], k = 0..8192 natural order
// ---------------------------------------------------------------------------
__global__ __launch_bounds__(1024) void fft_filter(
    const float* __restrict__ h, float2* __restrict__ hf)
{
    __shared__ float re[8704];
    __shared__ float im[8704];
    const int d = blockIdx.x;
    const int t = threadIdx.x;
    const float2* hrow = (const float2*)(h + (size_t)d * L_SZ);
    for (int n = t; n < 4096; n += 1024) { float2 z = hrow[n]; re[PD(n)] = z.x; im[PD(n)] = z.y; }
    for (int n = 4096 + t; n < 8192; n += 1024) { re[PD(n)] = 0.f; im[PD(n)] = 0.f; }
    __syncthreads();
    fft_fwd(re, im, t);
    float2* outp = hf + (size_t)d * HFS;
    for (int k = t; k < 8193; k += 1024) {
        const int ka = k & 8191;
        const int kb = (8192 - k) & 8191;
        const int p1 = PD(permP(ka)), p2 = PD(permP(kb));
        float zr = re[p1], zi = im[p1], wr2 = re[p2], wi2 = im[p2];
        float xer = 0.5f * (zr + wr2), xei = 0.5f * (zi - wi2);
        float xor_ = 0.5f * (zi + wi2), xoi = 0.5f * (wr2 - zr);
        float sn, cs;
        __sincosf(-ANGN * (float)k, &sn, &cs);
        float2 o;
        o.x = xer + (xor_ * cs - xoi * sn);
        o.y = xei + (xor_ * sn + xoi * cs);
        outp[k] = o;
    }
}

// ---------------------------------------------------------------------------
// per (b,d): y = irfft(rfft(v_pad)*hf[d])[:L]; gate with both dwconvs;
// write gatedT[d][b*L + l] (bf16)
// ---------------------------------------------------------------------------
__global__ __launch_bounds__(1024) void fft_conv(
    const float* __restrict__ vy, const float2* __restrict__ hf,
    const bf16* __restrict__ raw0, const bf16* __restrict__ raw1,
    const float* __restrict__ cw0, const float* __restrict__ cb0,
    const float* __restrict__ cw1, const float* __restrict__ cb1,
    bf16* __restrict__ gatedT)
{
    __shared__ float re[8704];
    __shared__ float im[8704];
    const int bid = blockIdx.x;
    const int d = bid >> 3, b = bid & 7;     // d-major: 8 blocks share H row
    const int t = threadIdx.x;
    const size_t rowoff = ((size_t)(b * 256 + d)) * L_SZ;
    const float2* row2c = (const float2*)(vy + rowoff);
    for (int n = t; n < 4096; n += 1024) { float2 z = row2c[n]; re[PD(n)] = z.x; im[PD(n)] = z.y; }
    for (int n = 4096 + t; n < 8192; n += 1024) { re[PD(n)] = 0.f; im[PD(n)] = 0.f; }
    __syncthreads();
    fft_fwd(re, im, t);
    const float2* H = hf + (size_t)d * HFS;
    if (t == 0) {
        float z0r = re[0], z0i = im[0];
        float x0 = z0r + z0i, xm = z0r - z0i;
        float2 h0 = H[0], hm = H[8192];
        float y0r = x0 * h0.x, y0i = x0 * h0.y;
        float ymr = xm * hm.x, ymi = xm * hm.y;
        float yer = 0.5f * (y0r + ymr), yei = 0.5f * (y0i + ymi);
        float yor = 0.5f * (y0r - ymr), yoi = 0.5f * (y0i - ymi);
        re[0] = yer - yoi;
        im[0] = yei + yor;
    }
#pragma unroll 4
    for (int j = 0; j < 4; ++j) {
        const int k = 1 + t + j * 1024;            // k in [1, 4096]
        const int mk = 8192 - k;
        const int p1 = PD(permP(k)), p2 = PD(permP(mk));
        float zr = re[p1], zi = im[p1], z2r = re[p2], z2i = im[p2];
        float xer = 0.5f * (zr + z2r), xei = 0.5f * (zi - z2i);
        float xor_ = 0.5f * (zi + z2i), xoi = 0.5f * (z2r - zr);
        float sn, cs;
        __sincosf(-ANGN * (float)k, &sn, &cs);
        float pr = xor_ * cs - xoi * sn, pi = xor_ * sn + xoi * cs;
        float xkr = xer + pr, xki = xei + pi;
        float xmr = xer - pr, xmi = pi - xei;
        float2 hk = H[k], hm = H[mk];
        float ykr = xkr * hk.x - xki * hk.y, yki = xkr * hk.y + xki * hk.x;
        float ymr = xmr * hm.x - xmi * hm.y, ymi = xmr * hm.y + xmi * hm.x;
        float yer = 0.5f * (ykr + ymr), yei = 0.5f * (yki - ymi);
        float dmr = 0.5f * (ykr - ymr), dmi = 0.5f * (yki + ymi);
        float yor = dmr * cs + dmi * sn;
        float yoi = dmi * cs - dmr * sn;
        re[p1] = yer - yoi;
        im[p1] = yei + yor;
        re[p2] = yer + yoi;
        im[p2] = yor - yei;
    }
    __syncthreads();
    fft_inv(re, im, t);
    // fused gating epilogue
    const float sc = 1.0f / 8192.0f;
    const float w00 = cw0[d * 3], w01 = cw0[d * 3 + 1], w02 = cw0[d * 3 + 2], bi0 = cb0[d];
    const float w10 = cw1[d * 3], w11 = cw1[d * 3 + 1], w12 = cw1[d * 3 + 2], bi1 = cb1[d];
    const bf16* r0 = raw0 + rowoff;
    const bf16* r1 = raw1 + rowoff;
    ushort* gout = (ushort*)gatedT + ((size_t)d * 65536 + b * 8192);
#pragma unroll
    for (int j = 0; j < 4; ++j) {
        const int n = t + j * 1024;
        const int l = 2 * n;
        const float y0 = re[PD(n)] * sc;
        const float y1 = im[PD(n)] * sc;
        float c0m = (l > 0) ? b2f(r0[l - 1]) : 0.f;
        float c0a = b2f(r0[l]);
        float c0b_ = b2f(r0[l + 1]);
        float c0p = (l + 2 < 8192) ? b2f(r0[l + 2]) : 0.f;
        float c1m = (l > 0) ? b2f(r1[l - 1]) : 0.f;
        float c1a = b2f(r1[l]);
        float c1b_ = b2f(r1[l + 1]);
        float c1p = (l + 2 < 8192) ? b2f(r1[l + 2]) : 0.f;
        float g00 = w00 * c0m + w01 * c0a + w02 * c0b_ + bi0;
        float g01 = w00 * c0a + w01 * c0b_ + w02 * c0p + bi0;
        float g10 = w10 * c1m + w11 * c1a + w12 * c1b_ + bi1;
        float g11 = w10 * c1a + w11 * c1b_ + w12 * c1p + bi1;
        bf16 o0 = f2b(y0 * g00 * g10);
        bf16 o1 = f2b(y1 * g01 * g11);
        ushort2 pk;
        pk.x = *(ushort*)&o0; pk.y = *(ushort*)&o1;
        *(ushort2*)(gout + l) = pk;
    }
}

// ---------------------------------------------------------------------------
// gatedT[256][65536] -> gated[65536][256]  (bf16 transpose, 64x64 tiles)
// ---------------------------------------------------------------------------
__global__ __launch_bounds__(256) void transpose_k(
    const ushort* __restrict__ gatedT, ushort* __restrict__ gated)
{
    __shared__ ushort T2[64 * 66];
    const int tid = threadIdx.x;
    const int m0 = blockIdx.x * 64, d0 = blockIdx.y * 64;
    const int rr = tid >> 3, co = (tid & 7) * 8;
#pragma unroll
    for (int it = 0; it < 2; ++it) {
        const int dr = rr + 32 * it;
        const uint4 val = *(const uint4*)(gatedT + (size_t)(d0 + dr) * 65536 + m0 + co);
        const ushort* vs = (const ushort*)&val;
#pragma unroll
        for (int i = 0; i < 8; ++i)
            T2[(co + i) * 66 + dr] = vs[i];
    }
    __syncthreads();
#pragma unroll
    for (int it = 0; it < 2; ++it) {
        const int mr = rr + 32 * it;
        uint w0 = *(const uint*)(T2 + mr * 66 + co);
        uint w1 = *(const uint*)(T2 + mr * 66 + co + 2);
        uint w2 = *(const uint*)(T2 + mr * 66 + co + 4);
        uint w3 = *(const uint*)(T2 + mr * 66 + co + 6);
        uint4 ov; ov.x = w0; ov.y = w1; ov.z = w2; ov.w = w3;
        *(uint4*)(gated + (size_t)(m0 + mr) * 256 + d0 + co) = ov;
    }
}

// ---------------------------------------------------------------------------
extern "C" void kernel_launch(void* const* d_in, const int* in_sizes, int n_in,
                              void* d_out, int out_size, void* d_ws, size_t ws_size,
                              hipStream_t stream)
{
    const float* x    = (const float*)d_in[0];
    const float* inW  = (const float*)d_in[1];
    const float* inb  = (const float*)d_in[2];
    const float* c0W  = (const float*)d_in[3];
    const float* c0b  = (const float*)d_in[4];
    const float* c1W  = (const float*)d_in[5];
    const float* c1b  = (const float*)d_in[6];
    const float* mW1  = (const float*)d_in[7];
    const float* mb1  = (const float*)d_in[8];
    const float* mW2  = (const float*)d_in[9];
    const float* mb2  = (const float*)d_in[10];
    const float* oW   = (const float*)d_in[11];
    const float* ob   = (const float*)d_in[12];
    const float* tpos = (const float*)d_in[13];
    float* out = (float*)d_out;

    char* ws = (char*)d_ws;
    // overlapping lifetime plan (max 185 MB):
    //   h [0,8MB) lives before gemm_proj writes v [0,64MB)
    //   gated [0,32MB) reuses v after fft_conv
    //   gatedT reuses xb region after gemm_proj
    float*  h      = (float*)(ws);                   // 8 MB   (phase: build_h/fft_filter)
    float*  v      = (float*)(ws);                   // 64 MB  [B][D][L] fp32
    bf16*   gated  = (bf16*)(ws);                    // 32 MB  [B*L][D] (after fft_conv)
    bf16*   raw0   = (bf16*)(ws + 67108864);         // 32 MB
    bf16*   raw1   = (bf16*)(ws + 100663296);        // 32 MB
    bf16*   xb     = (bf16*)(ws + 134217728);        // 32 MB  bf16 x
    bf16*   gatedT = (bf16*)(ws + 134217728);        // 32 MB  [D][B*L] (reuses xb)
    bf16*   inWb   = (bf16*)(ws + 167772160);        // 384 KB
    bf16*   outWb  = (bf16*)(ws + 168165376);        // 128 KB
    float2* hf     = (float2*)(ws + 168296448);      // 16.78 MB [D][HFS]

    prep_cast<<<8320, 256, 0, stream>>>(x, inW, oW, xb, inWb, outWb);
    build_h<<<256, 256, 0, stream>>>(tpos, mW1, mb1, mW2, mb2, h);
    fft_filter<<<256, 1024, 0, stream>>>(h, hf);
    gemm_proj<<<dim3(12, 256), 256, 0, stream>>>(xb, inWb, inb, v, raw0, raw1);
    fft_conv<<<2048, 1024, 0, stream>>>(v, hf, raw0, raw1, c0W, c0b, c1W, c1b, gatedT);
    transpose_k<<<dim3(1024, 4), 256, 0, stream>>>((const ushort*)gatedT, (ushort*)gated);
    gemm_out_k<<<dim3(4, 256), 256, 0, stream>>>(gated, outWb, ob, out);
}

// Round 4
// 452.946 us; speedup vs baseline: 1.5463x; 1.2774x over previous
//
#include <hip/hip_runtime.h>
#include <hip/hip_bf16.h>

typedef __hip_bfloat16 bf16;
typedef __attribute__((ext_vector_type(8))) short short8;
typedef __attribute__((ext_vector_type(4))) float floatx4;

#define L_SZ 8192
#define HFS 8193        // hf row stride in float2
#define PD(i) ((i) + ((i) >> 4))           // FFT LDS pad
#define SWZ(row, col) ((row) * 64 + ((col) ^ (((row) & 7) * 8)))   // GEMM LDS swizzle

__device__ __forceinline__ float b2f(bf16 x) { return __bfloat162float(x); }
__device__ __forceinline__ bf16 f2b(float x) { return __float2bfloat16(x); }
__device__ __forceinline__ float bs2f(short s) {
    return __uint_as_float(((unsigned int)(unsigned short)s) << 16);
}
__device__ __forceinline__ short f2bs(float x) {
    bf16 b = __float2bfloat16(x);
    return *reinterpret_cast<short*>(&b);
}
__device__ __forceinline__ short8 pack8(float4 a, float4 b) {
    short8 r;
    r[0] = f2bs(a.x); r[1] = f2bs(a.y); r[2] = f2bs(a.z); r[3] = f2bs(a.w);
    r[4] = f2bs(b.x); r[5] = f2bs(b.y); r[6] = f2bs(b.z); r[7] = f2bs(b.w);
    return r;
}

// storage position of frequency k after DIF stages radix [8,8,8,8,2]
__device__ __forceinline__ int permP(int k) {
    return ((k & 7) << 10) | (((k >> 3) & 7) << 7) | (((k >> 6) & 7) << 4)
         | (((k >> 9) & 7) << 1) | ((k >> 12) & 1);
}

// ---------------------------------------------------------------------------
// 8-point DFT, SF=-1 forward, SF=+1 inverse
// ---------------------------------------------------------------------------
template<int SF>
__device__ __forceinline__ void dft8(const float xr[8], const float xi[8],
                                     float yr[8], float yi[8]) {
    constexpr float sgn = (SF < 0) ? -1.f : 1.f;
    const float S2 = 0.70710678118654752f;
    float t0r=xr[0]+xr[4], t0i=xi[0]+xi[4];
    float t1r=xr[0]-xr[4], t1i=xi[0]-xi[4];
    float t2r=xr[2]+xr[6], t2i=xi[2]+xi[6];
    float t3r=xr[2]-xr[6], t3i=xi[2]-xi[6];
    float u0r=xr[1]+xr[5], u0i=xi[1]+xi[5];
    float u1r=xr[1]-xr[5], u1i=xi[1]-xi[5];
    float u2r=xr[3]+xr[7], u2i=xi[3]+xi[7];
    float u3r=xr[3]-xr[7], u3i=xi[3]-xi[7];
    float m3r = -sgn*t3i, m3i = sgn*t3r;
    float n3r = -sgn*u3i, n3i = sgn*u3r;
    float E0r=t0r+t2r, E0i=t0i+t2i, E2r=t0r-t2r, E2i=t0i-t2i;
    float E1r=t1r+m3r, E1i=t1i+m3i, E3r=t1r-m3r, E3i=t1i-m3i;
    float O0r=u0r+u2r, O0i=u0i+u2i, O2r=u0r-u2r, O2i=u0i-u2i;
    float O1r=u1r+n3r, O1i=u1i+n3i, O3r=u1r-n3r, O3i=u1i-n3i;
    float a1r = S2*(O1r - sgn*O1i),  a1i = S2*(O1i + sgn*O1r);
    float a2r = -sgn*O2i,            a2i = sgn*O2r;
    float a3r = S2*(-O3r - sgn*O3i), a3i = S2*(sgn*O3r - O3i);
    yr[0]=E0r+O0r; yi[0]=E0i+O0i; yr[4]=E0r-O0r; yi[4]=E0i-O0i;
    yr[1]=E1r+a1r; yi[1]=E1i+a1i; yr[5]=E1r-a1r; yi[5]=E1i-a1i;
    yr[2]=E2r+a2r; yi[2]=E2i+a2i; yr[6]=E2r-a2r; yi[6]=E2i-a2i;
    yr[3]=E3r+a3r; yi[3]=E3i+a3i; yr[7]=E3r-a3r; yi[7]=E3i-a3i;
}

template<int M>
__device__ __forceinline__ void stage8_fwd(float* re, float* im, int t) {
    constexpr int ST = M / 8;
    const int k = t & (ST - 1);
    const int i1 = ((t & ~(ST - 1)) << 3) | k;
    float xr[8], xi[8];
#pragma unroll
    for (int j = 0; j < 8; ++j) { int a = PD(i1 + j * ST); xr[j] = re[a]; xi[j] = im[a]; }
    float yr[8], yi[8];
    dft8<-1>(xr, xi, yr, yi);
    float c1, s1;
    __sincosf(-6.283185307179586f * (float)k / (float)M, &s1, &c1);
    float wr = c1, wi = s1;
#pragma unroll
    for (int jp = 1; jp < 8; ++jp) {
        float a = yr[jp], b = yi[jp];
        yr[jp] = a * wr - b * wi;
        yi[jp] = a * wi + b * wr;
        float nr = wr * c1 - wi * s1, ni = wr * s1 + wi * c1;
        wr = nr; wi = ni;
    }
#pragma unroll
    for (int j = 0; j < 8; ++j) { int a = PD(i1 + j * ST); re[a] = yr[j]; im[a] = yi[j]; }
}

template<int M>
__device__ __forceinline__ void stage8_inv(float* re, float* im, int t) {
    constexpr int ST = M / 8;
    const int k = t & (ST - 1);
    const int i1 = ((t & ~(ST - 1)) << 3) | k;
    float xr[8], xi[8];
#pragma unroll
    for (int j = 0; j < 8; ++j) { int a = PD(i1 + j * ST); xr[j] = re[a]; xi[j] = im[a]; }
    float c1, s1;
    __sincosf(6.283185307179586f * (float)k / (float)M, &s1, &c1);
    float wr = c1, wi = s1;
#pragma unroll
    for (int j = 1; j < 8; ++j) {
        float a = xr[j], b = xi[j];
        xr[j] = a * wr - b * wi;
        xi[j] = a * wi + b * wr;
        float nr = wr * c1 - wi * s1, ni = wr * s1 + wi * c1;
        wr = nr; wi = ni;
    }
    float yr[8], yi[8];
    dft8<1>(xr, xi, yr, yi);
#pragma unroll
    for (int j = 0; j < 8; ++j) { int a = PD(i1 + j * ST); re[a] = yr[j]; im[a] = yi[j]; }
}

__device__ __forceinline__ void stage2(float* re, float* im, int t) {
#pragma unroll
    for (int j = 0; j < 4; ++j) {
        const int i = t + j * 1024;
        const int a = PD(2 * i), b = PD(2 * i + 1);
        float ur = re[a], ui = im[a], vr = re[b], vi = im[b];
        re[a] = ur + vr; im[a] = ui + vi;
        re[b] = ur - vr; im[b] = ui - vi;
    }
}

__device__ __forceinline__ void fft_fwd(float* re, float* im, int t) {
    stage8_fwd<8192>(re, im, t); __syncthreads();
    stage8_fwd<1024>(re, im, t); __syncthreads();
    stage8_fwd<128>(re, im, t);  __syncthreads();
    stage8_fwd<16>(re, im, t);   __syncthreads();
    stage2(re, im, t);           __syncthreads();
}
__device__ __forceinline__ void fft_inv(float* re, float* im, int t) {
    stage2(re, im, t);           __syncthreads();
    stage8_inv<16>(re, im, t);   __syncthreads();
    stage8_inv<128>(re, im, t);  __syncthreads();
    stage8_inv<1024>(re, im, t); __syncthreads();
    stage8_inv<8192>(re, im, t); __syncthreads();
}

#define ANGN 3.83495197e-4f   // 2*pi/16384

// ---------------------------------------------------------------------------
// GEMM A: proj[n, m] = sum_k in_W[n,k] * x[m,k] + in_b[n]
// fp32 x/W read directly, bf16-packed during LDS staging.
// XCD-affine swizzle: 12 bn-blocks sharing one x-tile run on the same XCD.
// Output: proj[seg][b*256+c][l] bf16, seg 0=v, 1=raw0, 2=raw1
// ---------------------------------------------------------------------------
__global__ __launch_bounds__(256) void gemm_proj(
    const float* __restrict__ x, const float* __restrict__ inW, const float* __restrict__ inb,
    bf16* __restrict__ proj)
{
    __shared__ __align__(16) short sW[64 * 64];
    __shared__ __align__(16) short sX[256 * 64];
    const int tid = threadIdx.x;
    const int wave = tid >> 6, lane = tid & 63, quad = lane >> 4, l16 = lane & 15;
    const int id = blockIdx.x;
    const int xcd = id & 7, chunk = id >> 3;
    const int bn = (chunk % 12) * 64;
    const int bm = ((chunk / 12) * 8 + xcd) * 256;

    floatx4 acc[4][4];
#pragma unroll
    for (int i = 0; i < 4; ++i)
#pragma unroll
        for (int j = 0; j < 4; ++j) acc[i][j] = (floatx4){0.f, 0.f, 0.f, 0.f};

    const int r0 = tid >> 3, c0 = (tid & 7) * 8;
    for (int s = 0; s < 4; ++s) {
        const int koff = s * 64;
        short8 wreg[2], xreg[8];
#pragma unroll
        for (int j = 0; j < 2; ++j) {
            const float* p = inW + (size_t)(bn + j * 32 + r0) * 256 + koff + c0;
            wreg[j] = pack8(*(const float4*)p, *(const float4*)(p + 4));
        }
#pragma unroll
        for (int j = 0; j < 8; ++j) {
            const float* p = x + (size_t)(bm + j * 32 + r0) * 256 + koff + c0;
            xreg[j] = pack8(*(const float4*)p, *(const float4*)(p + 4));
        }
        __syncthreads();
#pragma unroll
        for (int j = 0; j < 2; ++j)
            *(short8*)(&sW[SWZ(j * 32 + r0, c0)]) = wreg[j];
#pragma unroll
        for (int j = 0; j < 8; ++j)
            *(short8*)(&sX[SWZ(j * 32 + r0, c0)]) = xreg[j];
        __syncthreads();
#pragma unroll
        for (int kk = 0; kk < 64; kk += 32) {
            const int ko = kk + quad * 8;
            short8 wf[4], xf[4];
#pragma unroll
            for (int ts = 0; ts < 4; ++ts)
                wf[ts] = *(const short8*)(&sW[SWZ(ts * 16 + l16, ko)]);
#pragma unroll
            for (int tb = 0; tb < 4; ++tb)
                xf[tb] = *(const short8*)(&sX[SWZ(wave * 64 + tb * 16 + l16, ko)]);
#pragma unroll
            for (int ts = 0; ts < 4; ++ts)
#pragma unroll
                for (int tb = 0; tb < 4; ++tb)
                    acc[ts][tb] = __builtin_amdgcn_mfma_f32_16x16x32_bf16(
                        wf[ts], xf[tb], acc[ts][tb], 0, 0, 0);
        }
    }
    const int seg = bn >> 8;
#pragma unroll
    for (int ts = 0; ts < 4; ++ts) {
#pragma unroll
        for (int r = 0; r < 4; ++r) {
            const int nglob = bn + ts * 16 + quad * 4 + r;
            const float bias = inb[nglob];
            const int c = nglob & 255;
#pragma unroll
            for (int tb = 0; tb < 4; ++tb) {
                const int m = bm + wave * 64 + tb * 16 + l16;
                const int bb = m >> 13, l = m & 8191;
                const size_t idx = ((size_t)(seg * 2048 + bb * 256 + c)) * 8192 + l;
                proj[idx] = f2b(acc[ts][tb][r] + bias);
            }
        }
    }
}

// ---------------------------------------------------------------------------
// GEMM F: out[m, n] = sum_k gated[m,k] * out_W[n,k] + out_b[n]
// ---------------------------------------------------------------------------
__global__ __launch_bounds__(256) void gemm_out_k(
    const bf16* __restrict__ gated, const float* __restrict__ outW, const float* __restrict__ outb,
    float* __restrict__ out)
{
    __shared__ __align__(16) short sW[64 * 64];
    __shared__ __align__(16) short sA[256 * 64];
    const int tid = threadIdx.x;
    const int wave = tid >> 6, lane = tid & 63, quad = lane >> 4, l16 = lane & 15;
    const int id = blockIdx.x;
    const int xcd = id & 7, chunk = id >> 3;
    const int bn = (chunk & 3) * 64;
    const int bm = ((chunk >> 2) * 8 + xcd) * 256;

    floatx4 acc[4][4]; // [tb(m)][ts(n)]
#pragma unroll
    for (int i = 0; i < 4; ++i)
#pragma unroll
        for (int j = 0; j < 4; ++j) acc[i][j] = (floatx4){0.f, 0.f, 0.f, 0.f};

    const int r0 = tid >> 3, c0 = (tid & 7) * 8;
    for (int s = 0; s < 4; ++s) {
        const int koff = s * 64;
        short8 wreg[2];
        uint4 areg[8];
#pragma unroll
        for (int j = 0; j < 2; ++j) {
            const float* p = outW + (size_t)(bn + j * 32 + r0) * 256 + koff + c0;
            wreg[j] = pack8(*(const float4*)p, *(const float4*)(p + 4));
        }
#pragma unroll
        for (int j = 0; j < 8; ++j)
            areg[j] = *(const uint4*)(gated + (size_t)(bm + j * 32 + r0) * 256 + koff + c0);
        __syncthreads();
#pragma unroll
        for (int j = 0; j < 2; ++j)
            *(short8*)(&sW[SWZ(j * 32 + r0, c0)]) = wreg[j];
#pragma unroll
        for (int j = 0; j < 8; ++j)
            *(uint4*)(&sA[SWZ(j * 32 + r0, c0)]) = areg[j];
        __syncthreads();
#pragma unroll
        for (int kk = 0; kk < 64; kk += 32) {
            const int ko = kk + quad * 8;
            short8 bfr[4], af[4];
#pragma unroll
            for (int ts = 0; ts < 4; ++ts)
                bfr[ts] = *(const short8*)(&sW[SWZ(ts * 16 + l16, ko)]);
#pragma unroll
            for (int tb = 0; tb < 4; ++tb)
                af[tb] = *(const short8*)(&sA[SWZ(wave * 64 + tb * 16 + l16, ko)]);
#pragma unroll
            for (int tb = 0; tb < 4; ++tb)
#pragma unroll
                for (int ts = 0; ts < 4; ++ts)
                    acc[tb][ts] = __builtin_amdgcn_mfma_f32_16x16x32_bf16(
                        af[tb], bfr[ts], acc[tb][ts], 0, 0, 0);
        }
    }
#pragma unroll
    for (int tb = 0; tb < 4; ++tb) {
#pragma unroll
        for (int r = 0; r < 4; ++r) {
            const int m = bm + wave * 64 + tb * 16 + quad * 4 + r;
#pragma unroll
            for (int ts = 0; ts < 4; ++ts) {
                const int n = bn + ts * 16 + l16;
                out[(size_t)m * 256 + n] = acc[tb][ts][r] + outb[n];
            }
        }
    }
}

// ---------------------------------------------------------------------------
// h[d, l] = silu(t_l*W1 + b1) @ W2[d,:] + b2[d]   (all fp32)
// ---------------------------------------------------------------------------
__global__ __launch_bounds__(256) void build_h(
    const float* __restrict__ tpos, const float* __restrict__ W1, const float* __restrict__ b1,
    const float* __restrict__ W2, const float* __restrict__ b2, float* __restrict__ h)
{
    __shared__ float s[32][64];
    __shared__ float tr[256 * 32];
    const int tid = threadIdx.x;
    const int l0 = blockIdx.x * 32;
#pragma unroll
    for (int p = 0; p < 8; ++p) {
        int idx = tid + p * 256;
        int li = idx >> 6, j = idx & 63;
        float tv = tpos[l0 + li];
        float z = tv * W1[j] + b1[j];
        s[li][j] = z / (1.f + __expf(-z));
    }
    __syncthreads();
    const int d = tid;
    float acc[32];
    float bb = b2[d];
#pragma unroll
    for (int li = 0; li < 32; ++li) acc[li] = bb;
    for (int j = 0; j < 64; ++j) {
        float w = W2[d * 64 + j];
#pragma unroll
        for (int li = 0; li < 32; ++li) acc[li] += w * s[li][j];
    }
#pragma unroll
    for (int li = 0; li < 32; ++li) tr[d * 32 + li] = acc[li];
    __syncthreads();
#pragma unroll
    for (int p = 0; p < 8; ++p) {
        int idx = tid + p * 256;
        int row = idx >> 3, c = (idx & 7) * 4;
        *(float4*)(h + (size_t)row * 8192 + l0 + c) = *(const float4*)(&tr[row * 32 + c]);
    }
}

// ---------------------------------------------------------------------------
// hf[d][k] = rfft_16384(h[d])[k], k = 0..8192 natural order
// ---------------------------------------------------------------------------
__global__ __launch_bounds__(1024) void fft_filter(
    const float* __restrict__ h, float2* __restrict__ hf)
{
    __shared__ float re[8704];
    __shared__ float im[8704];
    const int d = blockIdx.x;
    const int t = threadIdx.x;
    const float2* hrow = (const float2*)(h + (size_t)d * L_SZ);
    for (int n = t; n < 4096; n += 1024) { float2 z = hrow[n]; re[PD(n)] = z.x; im[PD(n)] = z.y; }
    for (int n = 4096 + t; n < 8192; n += 1024) { re[PD(n)] = 0.f; im[PD(n)] = 0.f; }
    __syncthreads();
    fft_fwd(re, im, t);
    float2* outp = hf + (size_t)d * HFS;
    for (int k = t; k < 8193; k += 1024) {
        const int ka = k & 8191;
        const int kb = (8192 - k) & 8191;
        const int p1 = PD(permP(ka)), p2 = PD(permP(kb));
        float zr = re[p1], zi = im[p1], wr2 = re[p2], wi2 = im[p2];
        float xer = 0.5f * (zr + wr2), xei = 0.5f * (zi - wi2);
        float xor_ = 0.5f * (zi + wi2), xoi = 0.5f * (wr2 - zr);
        float sn, cs;
        __sincosf(-ANGN * (float)k, &sn, &cs);
        float2 o;
        o.x = xer + (xor_ * cs - xoi * sn);
        o.y = xei + (xor_ * sn + xoi * cs);
        outp[k] = o;
    }
}

// ---------------------------------------------------------------------------
// per (b,d): y = irfft(rfft(v_pad)*hf[d])[:L]; gate with both dwconvs;
// write gatedT[d][b*L + l] (bf16).  v is bf16 (proj seg 0).
// ---------------------------------------------------------------------------
__global__ __launch_bounds__(1024) void fft_conv(
    const bf16* __restrict__ proj, const float2* __restrict__ hf,
    const float* __restrict__ cw0, const float* __restrict__ cb0,
    const float* __restrict__ cw1, const float* __restrict__ cb1,
    bf16* __restrict__ gatedT)
{
    __shared__ float re[8704];
    __shared__ float im[8704];
    const int bid = blockIdx.x;
    const int d = bid >> 3, b = bid & 7;     // d-major: 8 blocks share H row
    const int t = threadIdx.x;
    const size_t rowoff = ((size_t)(b * 256 + d)) * L_SZ;
    const short8 sv = *(const short8*)(proj + rowoff + 8 * (size_t)t);
#pragma unroll
    for (int j = 0; j < 4; ++j) {
        re[PD(4 * t + j)] = bs2f(sv[2 * j]);
        im[PD(4 * t + j)] = bs2f(sv[2 * j + 1]);
    }
    for (int n = 4096 + t; n < 8192; n += 1024) { re[PD(n)] = 0.f; im[PD(n)] = 0.f; }
    __syncthreads();
    fft_fwd(re, im, t);
    const float2* H = hf + (size_t)d * HFS;
    if (t == 0) {
        float z0r = re[0], z0i = im[0];
        float x0 = z0r + z0i, xm = z0r - z0i;
        float2 h0 = H[0], hm = H[8192];
        float y0r = x0 * h0.x, y0i = x0 * h0.y;
        float ymr = xm * hm.x, ymi = xm * hm.y;
        float yer = 0.5f * (y0r + ymr), yei = 0.5f * (y0i + ymi);
        float yor = 0.5f * (y0r - ymr), yoi = 0.5f * (y0i - ymi);
        re[0] = yer - yoi;
        im[0] = yei + yor;
    }
#pragma unroll 4
    for (int j = 0; j < 4; ++j) {
        const int k = 1 + t + j * 1024;            // k in [1, 4096]
        const int mk = 8192 - k;
        const int p1 = PD(permP(k)), p2 = PD(permP(mk));
        float zr = re[p1], zi = im[p1], z2r = re[p2], z2i = im[p2];
        float xer = 0.5f * (zr + z2r), xei = 0.5f * (zi - z2i);
        float xor_ = 0.5f * (zi + z2i), xoi = 0.5f * (z2r - zr);
        float sn, cs;
        __sincosf(-ANGN * (float)k, &sn, &cs);
        float pr = xor_ * cs - xoi * sn, pi = xor_ * sn + xoi * cs;
        float xkr = xer + pr, xki = xei + pi;
        float xmr = xer - pr, xmi = pi - xei;
        float2 hk = H[k], hm = H[mk];
        float ykr = xkr * hk.x - xki * hk.y, yki = xkr * hk.y + xki * hk.x;
        float ymr = xmr * hm.x - xmi * hm.y, ymi = xmr * hm.y + xmi * hm.x;
        float yer = 0.5f * (ykr + ymr), yei = 0.5f * (yki - ymi);
        float dmr = 0.5f * (ykr - ymr), dmi = 0.5f * (yki + ymi);
        float yor = dmr * cs + dmi * sn;
        float yoi = dmi * cs - dmr * sn;
        re[p1] = yer - yoi;
        im[p1] = yei + yor;
        re[p2] = yer + yoi;
        im[p2] = yor - yei;
    }
    __syncthreads();
    fft_inv(re, im, t);
    // fused gating epilogue
    const float sc = 1.0f / 8192.0f;
    const float w00 = cw0[d * 3], w01 = cw0[d * 3 + 1], w02 = cw0[d * 3 + 2], bi0 = cb0[d];
    const float w10 = cw1[d * 3], w11 = cw1[d * 3 + 1], w12 = cw1[d * 3 + 2], bi1 = cb1[d];
    const bf16* r0 = proj + (size_t)2048 * L_SZ + rowoff;   // raw0 plane
    const bf16* r1 = proj + (size_t)4096 * L_SZ + rowoff;   // raw1 plane
    ushort* gout = (ushort*)gatedT + ((size_t)d * 65536 + b * 8192);
#pragma unroll
    for (int j = 0; j < 4; ++j) {
        const int n = t + j * 1024;
        const int l = 2 * n;
        const float y0 = re[PD(n)] * sc;
        const float y1 = im[PD(n)] * sc;
        float c0m = (l > 0) ? b2f(r0[l - 1]) : 0.f;
        float c0a = b2f(r0[l]);
        float c0b_ = b2f(r0[l + 1]);
        float c0p = (l + 2 < 8192) ? b2f(r0[l + 2]) : 0.f;
        float c1m = (l > 0) ? b2f(r1[l - 1]) : 0.f;
        float c1a = b2f(r1[l]);
        float c1b_ = b2f(r1[l + 1]);
        float c1p = (l + 2 < 8192) ? b2f(r1[l + 2]) : 0.f;
        float g00 = w00 * c0m + w01 * c0a + w02 * c0b_ + bi0;
        float g01 = w00 * c0a + w01 * c0b_ + w02 * c0p + bi0;
        float g10 = w10 * c1m + w11 * c1a + w12 * c1b_ + bi1;
        float g11 = w10 * c1a + w11 * c1b_ + w12 * c1p + bi1;
        bf16 o0 = f2b(y0 * g00 * g10);
        bf16 o1 = f2b(y1 * g01 * g11);
        ushort2 pk;
        pk.x = *(ushort*)&o0; pk.y = *(ushort*)&o1;
        *(ushort2*)(gout + l) = pk;
    }
}

// ---------------------------------------------------------------------------
// gatedT[256][65536] -> gated[65536][256]  (bf16 transpose, 64x64 tiles)
// ---------------------------------------------------------------------------
__global__ __launch_bounds__(256) void transpose_k(
    const ushort* __restrict__ gatedT, ushort* __restrict__ gated)
{
    __shared__ ushort T2[64 * 66];
    const int tid = threadIdx.x;
    const int m0 = blockIdx.x * 64, d0 = blockIdx.y * 64;
    const int rr = tid >> 3, co = (tid & 7) * 8;
#pragma unroll
    for (int it = 0; it < 2; ++it) {
        const int dr = rr + 32 * it;
        const uint4 val = *(const uint4*)(gatedT + (size_t)(d0 + dr) * 65536 + m0 + co);
        const ushort* vs = (const ushort*)&val;
#pragma unroll
        for (int i = 0; i < 8; ++i)
            T2[(co + i) * 66 + dr] = vs[i];
    }
    __syncthreads();
#pragma unroll
    for (int it = 0; it < 2; ++it) {
        const int mr = rr + 32 * it;
        uint w0 = *(const uint*)(T2 + mr * 66 + co);
        uint w1 = *(const uint*)(T2 + mr * 66 + co + 2);
        uint w2 = *(const uint*)(T2 + mr * 66 + co + 4);
        uint w3 = *(const uint*)(T2 + mr * 66 + co + 6);
        uint4 ov; ov.x = w0; ov.y = w1; ov.z = w2; ov.w = w3;
        *(uint4*)(gated + (size_t)(m0 + mr) * 256 + d0 + co) = ov;
    }
}

// ---------------------------------------------------------------------------
extern "C" void kernel_launch(void* const* d_in, const int* in_sizes, int n_in,
                              void* d_out, int out_size, void* d_ws, size_t ws_size,
                              hipStream_t stream)
{
    const float* x    = (const float*)d_in[0];
    const float* inW  = (const float*)d_in[1];
    const float* inb  = (const float*)d_in[2];
    const float* c0W  = (const float*)d_in[3];
    const float* c0b  = (const float*)d_in[4];
    const float* c1W  = (const float*)d_in[5];
    const float* c1b  = (const float*)d_in[6];
    const float* mW1  = (const float*)d_in[7];
    const float* mb1  = (const float*)d_in[8];
    const float* mW2  = (const float*)d_in[9];
    const float* mb2  = (const float*)d_in[10];
    const float* oW   = (const float*)d_in[11];
    const float* ob   = (const float*)d_in[12];
    const float* tpos = (const float*)d_in[13];
    float* out = (float*)d_out;

    char* ws = (char*)d_ws;
    // layout (peak 159.4 MB):
    //   proj [0, 96 MB): seg0=v(bf16), seg1=raw0, seg2=raw1
    //   gated reuses proj seg0 after fft_conv consumed it
    bf16*   proj   = (bf16*)(ws);                    // 96 MB [3][2048][8192]
    bf16*   gated  = (bf16*)(ws);                    // 32 MB [65536][256] (after fft_conv)
    bf16*   gatedT = (bf16*)(ws + 100663296);        // 32 MB [256][65536]
    float2* hf     = (float2*)(ws + 134217728);      // 16.78 MB [256][HFS]
    float*  h      = (float*)(ws + 150996992);       // 8 MB [256][8192]

    build_h<<<256, 256, 0, stream>>>(tpos, mW1, mb1, mW2, mb2, h);
    fft_filter<<<256, 1024, 0, stream>>>(h, hf);
    gemm_proj<<<3072, 256, 0, stream>>>(x, inW, inb, proj);
    fft_conv<<<2048, 1024, 0, stream>>>(proj, hf, c0W, c0b, c1W, c1b, gatedT);
    transpose_k<<<dim3(1024, 4), 256, 0, stream>>>((const ushort*)gatedT, (ushort*)gated);
    gemm_out_k<<<1024, 256, 0, stream>>>(gated, oW, ob, out);
}

// Round 6
// 412.251 us; speedup vs baseline: 1.6990x; 1.0987x over previous
//
#include <hip/hip_runtime.h>
#include <hip/hip_bf16.h>

typedef __hip_bfloat16 bf16;
typedef __attribute__((ext_vector_type(8))) short short8;
typedef __attribute__((ext_vector_type(4))) float floatx4;

#define L_SZ 8192
#define HFS 8193        // hf row stride in float2
#define PD2(i) ((i) + (((i) >> 4) << 1))   // float2 LDS pad: +2 per 16 (keeps pairs 16B-aligned)
#define SWZ(row, col) ((row) * 64 + ((col) ^ (((row) & 7) * 8)))   // GEMM LDS swizzle
#define ANGN 3.83495197e-4f    // 2*pi/16384
#define ANG8K 7.66990394e-4f   // 2*pi/8192

__device__ __forceinline__ float b2f(bf16 x) { return __bfloat162float(x); }
__device__ __forceinline__ bf16 f2b(float x) { return __float2bfloat16(x); }
__device__ __forceinline__ float lo2f(unsigned int u) { return __uint_as_float(u << 16); }
__device__ __forceinline__ float hi2f(unsigned int u) { return __uint_as_float(u & 0xffff0000u); }
__device__ __forceinline__ unsigned short f2bu(float x) {
    bf16 b = __float2bfloat16(x);
    return *reinterpret_cast<unsigned short*>(&b);
}
__device__ __forceinline__ short f2bs(float x) {
    bf16 b = __float2bfloat16(x);
    return *reinterpret_cast<short*>(&b);
}
__device__ __forceinline__ short8 pack8(float4 a, float4 b) {
    short8 r;
    r[0] = f2bs(a.x); r[1] = f2bs(a.y); r[2] = f2bs(a.z); r[3] = f2bs(a.w);
    r[4] = f2bs(b.x); r[5] = f2bs(b.y); r[6] = f2bs(b.z); r[7] = f2bs(b.w);
    return r;
}

// half-perm: storage position pair-base of frequency q (q<4096) after DIF [8,8,8,8,(2)]
__device__ __forceinline__ int P2h(int k) {
    return ((k & 7) << 9) | (((k >> 3) & 7) << 6) | (((k >> 6) & 7) << 3) | ((k >> 9) & 7);
}

// ---------------------------------------------------------------------------
// 8-point DFT, SF=-1 forward, SF=+1 inverse
// ---------------------------------------------------------------------------
template<int SF>
__device__ __forceinline__ void dft8(const float xr[8], const float xi[8],
                                     float yr[8], float yi[8]) {
    constexpr float sgn = (SF < 0) ? -1.f : 1.f;
    const float S2 = 0.70710678118654752f;
    float t0r=xr[0]+xr[4], t0i=xi[0]+xi[4];
    float t1r=xr[0]-xr[4], t1i=xi[0]-xi[4];
    float t2r=xr[2]+xr[6], t2i=xi[2]+xi[6];
    float t3r=xr[2]-xr[6], t3i=xi[2]-xi[6];
    float u0r=xr[1]+xr[5], u0i=xi[1]+xi[5];
    float u1r=xr[1]-xr[5], u1i=xi[1]-xi[5];
    float u2r=xr[3]+xr[7], u2i=xi[3]+xi[7];
    float u3r=xr[3]-xr[7], u3i=xi[3]-xi[7];
    float m3r = -sgn*t3i, m3i = sgn*t3r;
    float n3r = -sgn*u3i, n3i = sgn*u3r;
    float E0r=t0r+t2r, E0i=t0i+t2i, E2r=t0r-t2r, E2i=t0i-t2i;
    float E1r=t1r+m3r, E1i=t1i+m3i, E3r=t1r-m3r, E3i=t1i-m3i;
    float O0r=u0r+u2r, O0i=u0i+u2i, O2r=u0r-u2r, O2i=u0i-u2i;
    float O1r=u1r+n3r, O1i=u1i+n3i, O3r=u1r-n3r, O3i=u1i-n3i;
    float a1r = S2*(O1r - sgn*O1i),  a1i = S2*(O1i + sgn*O1r);
    float a2r = -sgn*O2i,            a2i = sgn*O2r;
    float a3r = S2*(-O3r - sgn*O3i), a3i = S2*(sgn*O3r - O3i);
    yr[0]=E0r+O0r; yi[0]=E0i+O0i; yr[4]=E0r-O0r; yi[4]=E0i-O0i;
    yr[1]=E1r+a1r; yi[1]=E1i+a1i; yr[5]=E1r-a1r; yi[5]=E1i-a1i;
    yr[2]=E2r+a2r; yi[2]=E2i+a2i; yr[6]=E2r-a2r; yi[6]=E2i-a2i;
    yr[3]=E3r+a3r; yi[3]=E3i+a3i; yr[7]=E3r-a3r; yi[7]=E3i-a3i;
}

// radix-8 DIF fwd stage on float2 LDS
template<int M>
__device__ __forceinline__ void s8f(float2* Z, int t) {
    constexpr int ST = M / 8;
    const int k = t & (ST - 1);
    const int i1 = ((t & ~(ST - 1)) << 3) | k;
    float xr[8], xi[8];
#pragma unroll
    for (int j = 0; j < 8; ++j) { float2 z = Z[PD2(i1 + j * ST)]; xr[j] = z.x; xi[j] = z.y; }
    float yr[8], yi[8];
    dft8<-1>(xr, xi, yr, yi);
    float c1, s1;
    __sincosf(-6.283185307179586f * (float)k / (float)M, &s1, &c1);
    float wr = c1, wi = s1;
#pragma unroll
    for (int jp = 1; jp < 8; ++jp) {
        float a = yr[jp], b = yi[jp];
        yr[jp] = a * wr - b * wi;
        yi[jp] = a * wi + b * wr;
        float nr = wr * c1 - wi * s1, ni = wr * s1 + wi * c1;
        wr = nr; wi = ni;
    }
#pragma unroll
    for (int j = 0; j < 8; ++j) Z[PD2(i1 + j * ST)] = make_float2(yr[j], yi[j]);
}

// radix-8 DIT inv stage on float2 LDS
template<int M>
__device__ __forceinline__ void s8i(float2* Z, int t) {
    constexpr int ST = M / 8;
    const int k = t & (ST - 1);
    const int i1 = ((t & ~(ST - 1)) << 3) | k;
    float xr[8], xi[8];
#pragma unroll
    for (int j = 0; j < 8; ++j) { float2 z = Z[PD2(i1 + j * ST)]; xr[j] = z.x; xi[j] = z.y; }
    float c1, s1;
    __sincosf(6.283185307179586f * (float)k / (float)M, &s1, &c1);
    float wr = c1, wi = s1;
#pragma unroll
    for (int j = 1; j < 8; ++j) {
        float a = xr[j], b = xi[j];
        xr[j] = a * wr - b * wi;
        xi[j] = a * wi + b * wr;
        float nr = wr * c1 - wi * s1, ni = wr * s1 + wi * c1;
        wr = nr; wi = ni;
    }
    float yr[8], yi[8];
    dft8<1>(xr, xi, yr, yi);
#pragma unroll
    for (int j = 0; j < 8; ++j) Z[PD2(i1 + j * ST)] = make_float2(yr[j], yi[j]);
}

// untangle pair (k, 8192-k), multiply by H, retangle.  (c,s) = e^{-2pi i k/16384}
__device__ __forceinline__ void umr(float2 z, float2 z2, float c, float s,
                                    float2 Hk, float2 Hm, float2& spk, float2& spm)
{
    float xer = 0.5f*(z.x + z2.x), xei = 0.5f*(z.y - z2.y);
    float xor_ = 0.5f*(z.y + z2.y), xoi = 0.5f*(z2.x - z.x);
    float pr = xor_*c - xoi*s, pi = xor_*s + xoi*c;
    float xkr = xer + pr, xki = xei + pi;
    float xmr = xer - pr, xmi = pi - xei;
    float ykr = xkr*Hk.x - xki*Hk.y, yki = xkr*Hk.y + xki*Hk.x;
    float ymr = xmr*Hm.x - xmi*Hm.y, ymi = xmr*Hm.y + xmi*Hm.x;
    float yer = 0.5f*(ykr + ymr), yei = 0.5f*(yki - ymi);
    float dmr = 0.5f*(ykr - ymr), dmi = 0.5f*(yki + ymi);
    float yor = dmr*c + dmi*s, yoi = dmi*c - dmr*s;
    spk = make_float2(yer - yoi, yei + yor);
    spm = make_float2(yer + yoi, yor - yei);
}

// untangle only (for filter spectrum)
__device__ __forceinline__ void unt2(float2 z, float2 z2, float c, float s,
                                     float2& Xk, float2& Xm)
{
    float xer = 0.5f*(z.x + z2.x), xei = 0.5f*(z.y - z2.y);
    float xor_ = 0.5f*(z.y + z2.y), xoi = 0.5f*(z2.x - z.x);
    float pr = xor_*c - xoi*s, pi = xor_*s + xoi*c;
    Xk = make_float2(xer + pr, xei + pi);
    Xm = make_float2(xer - pr, pi - xei);
}

// full orbit {q, q+4096, 8192-q, 4096-q}: stage2fwd + untangle + Hmul + retangle + stage2inv
__device__ __forceinline__ void orbit_conv(float2* Z, const float2* __restrict__ H, int q)
{
    const int pa = PD2(2 * P2h(q));
    const int pb = PD2(2 * P2h(4096 - q));
    float4 Af = *(const float4*)&Z[pa];
    float4 Bf = *(const float4*)&Z[pb];
    float2 Sq   = make_float2(Af.x + Af.z, Af.y + Af.w);   // S[q]
    float2 Sq4  = make_float2(Af.x - Af.z, Af.y - Af.w);   // S[q+4096]
    float2 Sk2  = make_float2(Bf.x + Bf.z, Bf.y + Bf.w);   // S[4096-q]
    float2 Smq  = make_float2(Bf.x - Bf.z, Bf.y - Bf.w);   // S[8192-q]
    float c, s;
    __sincosf(-ANGN * (float)q, &s, &c);
    float2 sp_q, sp_mq, sp_k2, sp_mk2;
    umr(Sq,  Smq, c,  s,  H[q],        H[8192 - q], sp_q,  sp_mq);
    umr(Sk2, Sq4, -s, -c, H[4096 - q], H[4096 + q], sp_k2, sp_mk2);
    float4 oa, ob;
    oa.x = sp_q.x + sp_mk2.x; oa.y = sp_q.y + sp_mk2.y;
    oa.z = sp_q.x - sp_mk2.x; oa.w = sp_q.y - sp_mk2.y;
    ob.x = sp_k2.x + sp_mq.x; ob.y = sp_k2.y + sp_mq.y;
    ob.z = sp_k2.x - sp_mq.x; ob.w = sp_k2.y - sp_mq.y;
    *(float4*)&Z[pa] = oa;
    *(float4*)&Z[pb] = ob;
}

__device__ __forceinline__ void orbit_filter(float2* Z, float2* __restrict__ out, int q)
{
    const int pa = PD2(2 * P2h(q));
    const int pb = PD2(2 * P2h(4096 - q));
    float4 Af = *(const float4*)&Z[pa];
    float4 Bf = *(const float4*)&Z[pb];
    float2 Sq   = make_float2(Af.x + Af.z, Af.y + Af.w);
    float2 Sq4  = make_float2(Af.x - Af.z, Af.y - Af.w);
    float2 Sk2  = make_float2(Bf.x + Bf.z, Bf.y + Bf.w);
    float2 Smq  = make_float2(Bf.x - Bf.z, Bf.y - Bf.w);
    float c, s;
    __sincosf(-ANGN * (float)q, &s, &c);
    float2 Xa, Xb, Xc2, Xd;
    unt2(Sq,  Smq, c,  s,  Xa, Xb);    // X[q], X[8192-q]
    unt2(Sk2, Sq4, -s, -c, Xc2, Xd);   // X[4096-q], X[4096+q]
    out[q] = Xa; out[8192 - q] = Xb; out[4096 - q] = Xc2; out[4096 + q] = Xd;
}

// ---------------------------------------------------------------------------
// GEMM A: proj[n, m] = sum_k in_W[n,k] * x[m,k] + in_b[n]
// XCD-affine swizzle; output proj[seg][b*256+c][l] bf16
// ---------------------------------------------------------------------------
__global__ __launch_bounds__(256) void gemm_proj(
    const float* __restrict__ x, const float* __restrict__ inW, const float* __restrict__ inb,
    bf16* __restrict__ proj)
{
    __shared__ __align__(16) short sW[64 * 64];
    __shared__ __align__(16) short sX[256 * 64];
    const int tid = threadIdx.x;
    const int wave = tid >> 6, lane = tid & 63, quad = lane >> 4, l16 = lane & 15;
    const int id = blockIdx.x;
    const int xcd = id & 7, chunk = id >> 3;
    const int bn = (chunk % 12) * 64;
    const int bm = ((chunk / 12) * 8 + xcd) * 256;

    floatx4 acc[4][4];
#pragma unroll
    for (int i = 0; i < 4; ++i)
#pragma unroll
        for (int j = 0; j < 4; ++j) acc[i][j] = (floatx4){0.f, 0.f, 0.f, 0.f};

    const int r0 = tid >> 3, c0 = (tid & 7) * 8;
    for (int s = 0; s < 4; ++s) {
        const int koff = s * 64;
        short8 wreg[2], xreg[8];
#pragma unroll
        for (int j = 0; j < 2; ++j) {
            const float* p = inW + (size_t)(bn + j * 32 + r0) * 256 + koff + c0;
            wreg[j] = pack8(*(const float4*)p, *(const float4*)(p + 4));
        }
#pragma unroll
        for (int j = 0; j < 8; ++j) {
            const float* p = x + (size_t)(bm + j * 32 + r0) * 256 + koff + c0;
            xreg[j] = pack8(*(const float4*)p, *(const float4*)(p + 4));
        }
        __syncthreads();
#pragma unroll
        for (int j = 0; j < 2; ++j)
            *(short8*)(&sW[SWZ(j * 32 + r0, c0)]) = wreg[j];
#pragma unroll
        for (int j = 0; j < 8; ++j)
            *(short8*)(&sX[SWZ(j * 32 + r0, c0)]) = xreg[j];
        __syncthreads();
#pragma unroll
        for (int kk = 0; kk < 64; kk += 32) {
            const int ko = kk + quad * 8;
            short8 wf[4], xf[4];
#pragma unroll
            for (int ts = 0; ts < 4; ++ts)
                wf[ts] = *(const short8*)(&sW[SWZ(ts * 16 + l16, ko)]);
#pragma unroll
            for (int tb = 0; tb < 4; ++tb)
                xf[tb] = *(const short8*)(&sX[SWZ(wave * 64 + tb * 16 + l16, ko)]);
#pragma unroll
            for (int ts = 0; ts < 4; ++ts)
#pragma unroll
                for (int tb = 0; tb < 4; ++tb)
                    acc[ts][tb] = __builtin_amdgcn_mfma_f32_16x16x32_bf16(
                        wf[ts], xf[tb], acc[ts][tb], 0, 0, 0);
        }
    }
    const int seg = bn >> 8;
#pragma unroll
    for (int ts = 0; ts < 4; ++ts) {
#pragma unroll
        for (int r = 0; r < 4; ++r) {
            const int nglob = bn + ts * 16 + quad * 4 + r;
            const float bias = inb[nglob];
            const int c = nglob & 255;
#pragma unroll
            for (int tb = 0; tb < 4; ++tb) {
                const int m = bm + wave * 64 + tb * 16 + l16;
                const int bb = m >> 13, l = m & 8191;
                const size_t idx = ((size_t)(seg * 2048 + bb * 256 + c)) * 8192 + l;
                proj[idx] = f2b(acc[ts][tb][r] + bias);
            }
        }
    }
}

// ---------------------------------------------------------------------------
// GEMM F: out[m, n] = sum_k gated[m,k] * out_W[n,k] + out_b[n]
// ---------------------------------------------------------------------------
__global__ __launch_bounds__(256) void gemm_out_k(
    const bf16* __restrict__ gated, const float* __restrict__ outW, const float* __restrict__ outb,
    float* __restrict__ out)
{
    __shared__ __align__(16) short sW[64 * 64];
    __shared__ __align__(16) short sA[256 * 64];
    const int tid = threadIdx.x;
    const int wave = tid >> 6, lane = tid & 63, quad = lane >> 4, l16 = lane & 15;
    const int id = blockIdx.x;
    const int xcd = id & 7, chunk = id >> 3;
    const int bn = (chunk & 3) * 64;
    const int bm = ((chunk >> 2) * 8 + xcd) * 256;

    floatx4 acc[4][4];
#pragma unroll
    for (int i = 0; i < 4; ++i)
#pragma unroll
        for (int j = 0; j < 4; ++j) acc[i][j] = (floatx4){0.f, 0.f, 0.f, 0.f};

    const int r0 = tid >> 3, c0 = (tid & 7) * 8;
    for (int s = 0; s < 4; ++s) {
        const int koff = s * 64;
        short8 wreg[2];
        uint4 areg[8];
#pragma unroll
        for (int j = 0; j < 2; ++j) {
            const float* p = outW + (size_t)(bn + j * 32 + r0) * 256 + koff + c0;
            wreg[j] = pack8(*(const float4*)p, *(const float4*)(p + 4));
        }
#pragma unroll
        for (int j = 0; j < 8; ++j)
            areg[j] = *(const uint4*)(gated + (size_t)(bm + j * 32 + r0) * 256 + koff + c0);
        __syncthreads();
#pragma unroll
        for (int j = 0; j < 2; ++j)
            *(short8*)(&sW[SWZ(j * 32 + r0, c0)]) = wreg[j];
#pragma unroll
        for (int j = 0; j < 8; ++j)
            *(uint4*)(&sA[SWZ(j * 32 + r0, c0)]) = areg[j];
        __syncthreads();
#pragma unroll
        for (int kk = 0; kk < 64; kk += 32) {
            const int ko = kk + quad * 8;
            short8 bfr[4], af[4];
#pragma unroll
            for (int ts = 0; ts < 4; ++ts)
                bfr[ts] = *(const short8*)(&sW[SWZ(ts * 16 + l16, ko)]);
#pragma unroll
            for (int tb = 0; tb < 4; ++tb)
                af[tb] = *(const short8*)(&sA[SWZ(wave * 64 + tb * 16 + l16, ko)]);
#pragma unroll
            for (int tb = 0; tb < 4; ++tb)
#pragma unroll
                for (int ts = 0; ts < 4; ++ts)
                    acc[tb][ts] = __builtin_amdgcn_mfma_f32_16x16x32_bf16(
                        af[tb], bfr[ts], acc[tb][ts], 0, 0, 0);
        }
    }
#pragma unroll
    for (int tb = 0; tb < 4; ++tb) {
#pragma unroll
        for (int r = 0; r < 4; ++r) {
            const int m = bm + wave * 64 + tb * 16 + quad * 4 + r;
#pragma unroll
            for (int ts = 0; ts < 4; ++ts) {
                const int n = bn + ts * 16 + l16;
                out[(size_t)m * 256 + n] = acc[tb][ts][r] + outb[n];
            }
        }
    }
}

// ---------------------------------------------------------------------------
// h[d, l] = silu(t_l*W1 + b1) @ W2[d,:] + b2[d]   (all fp32)
// ---------------------------------------------------------------------------
__global__ __launch_bounds__(256) void build_h(
    const float* __restrict__ tpos, const float* __restrict__ W1, const float* __restrict__ b1,
    const float* __restrict__ W2, const float* __restrict__ b2, float* __restrict__ h)
{
    __shared__ float s[32][64];
    __shared__ float tr[256 * 32];
    const int tid = threadIdx.x;
    const int l0 = blockIdx.x * 32;
#pragma unroll
    for (int p = 0; p < 8; ++p) {
        int idx = tid + p * 256;
        int li = idx >> 6, j = idx & 63;
        float tv = tpos[l0 + li];
        float z = tv * W1[j] + b1[j];
        s[li][j] = z / (1.f + __expf(-z));
    }
    __syncthreads();
    const int d = tid;
    float acc[32];
    float bb = b2[d];
#pragma unroll
    for (int li = 0; li < 32; ++li) acc[li] = bb;
    for (int j = 0; j < 64; ++j) {
        float w = W2[d * 64 + j];
#pragma unroll
        for (int li = 0; li < 32; ++li) acc[li] += w * s[li][j];
    }
#pragma unroll
    for (int li = 0; li < 32; ++li) tr[d * 32 + li] = acc[li];
    __syncthreads();
#pragma unroll
    for (int p = 0; p < 8; ++p) {
        int idx = tid + p * 256;
        int row = idx >> 3, c = (idx & 7) * 4;
        *(float4*)(h + (size_t)row * 8192 + l0 + c) = *(const float4*)(&tr[row * 32 + c]);
    }
}

// ---------------------------------------------------------------------------
// hf[d][k] = rfft_16384(h[d])[k], k=0..8192 natural order
// ---------------------------------------------------------------------------
__global__ __launch_bounds__(1024) void fft_filter(
    const float* __restrict__ h, float2* __restrict__ hf)
{
    __shared__ __align__(16) float2 Z[9216];
    const int d = blockIdx.x;
    const int t = threadIdx.x;
    const float2* hrow = (const float2*)(h + (size_t)d * L_SZ);
    // fused first stage (M=8192): inputs j>=4 are zero
    {
        float xr[8], xi[8];
#pragma unroll
        for (int j = 0; j < 4; ++j) { float2 z = hrow[t + (j << 10)]; xr[j] = z.x; xi[j] = z.y; }
#pragma unroll
        for (int j = 4; j < 8; ++j) { xr[j] = 0.f; xi[j] = 0.f; }
        float yr[8], yi[8];
        dft8<-1>(xr, xi, yr, yi);
        float c1, s1;
        __sincosf(-ANG8K * (float)t, &s1, &c1);
        float wr = c1, wi = s1;
#pragma unroll
        for (int jp = 1; jp < 8; ++jp) {
            float a = yr[jp], b = yi[jp];
            yr[jp] = a * wr - b * wi;
            yi[jp] = a * wi + b * wr;
            float nr = wr * c1 - wi * s1, ni = wr * s1 + wi * c1;
            wr = nr; wi = ni;
        }
#pragma unroll
        for (int j = 0; j < 8; ++j) Z[PD2(t + (j << 10))] = make_float2(yr[j], yi[j]);
    }
    __syncthreads();
    s8f<1024>(Z, t); __syncthreads();
    s8f<128>(Z, t);  __syncthreads();
    s8f<16>(Z, t);   __syncthreads();
    float2* outp = hf + (size_t)d * HFS;
    if (t == 0) {
        float4 Af = *(const float4*)&Z[0];
        float2 S0 = make_float2(Af.x + Af.z, Af.y + Af.w);
        float2 S4 = make_float2(Af.x - Af.z, Af.y - Af.w);
        outp[0]    = make_float2(S0.x + S0.y, 0.f);
        outp[8192] = make_float2(S0.x - S0.y, 0.f);
        outp[4096] = make_float2(S4.x, -S4.y);
        float4 Bf = *(const float4*)&Z[PD2(8)];
        float2 S2k = make_float2(Bf.x + Bf.z, Bf.y + Bf.w);
        float2 S6k = make_float2(Bf.x - Bf.z, Bf.y - Bf.w);
        const float R2 = 0.70710678118654752f;
        float2 Xa, Xb;
        unt2(S2k, S6k, R2, -R2, Xa, Xb);
        outp[2048] = Xa; outp[6144] = Xb;
    } else {
        orbit_filter(Z, outp, t);
    }
    orbit_filter(Z, outp, t + 1024);
}

// ---------------------------------------------------------------------------
// per (b,d): y = irfft(rfft(v)*hf[d])[:L]; gate with both dwconvs; write gatedT
// ---------------------------------------------------------------------------
__global__ __launch_bounds__(1024) void fft_conv(
    const bf16* __restrict__ proj, const float2* __restrict__ hf,
    const float* __restrict__ cw0, const float* __restrict__ cb0,
    const float* __restrict__ cw1, const float* __restrict__ cb1,
    bf16* __restrict__ gatedT)
{
    __shared__ __align__(16) float2 Z[9216];
    const int bid = blockIdx.x;
    const int d = bid >> 3, b = bid & 7;
    const int t = threadIdx.x;
    const size_t rowoff = ((size_t)(b * 256 + d)) * L_SZ;
    // fused first stage: bf16 v row -> complex packed, upper half zero
    {
        const unsigned int* vrow = (const unsigned int*)(proj + rowoff);
        float xr[8], xi[8];
#pragma unroll
        for (int j = 0; j < 4; ++j) {
            unsigned int u = vrow[t + (j << 10)];
            xr[j] = lo2f(u); xi[j] = hi2f(u);
        }
#pragma unroll
        for (int j = 4; j < 8; ++j) { xr[j] = 0.f; xi[j] = 0.f; }
        float yr[8], yi[8];
        dft8<-1>(xr, xi, yr, yi);
        float c1, s1;
        __sincosf(-ANG8K * (float)t, &s1, &c1);
        float wr = c1, wi = s1;
#pragma unroll
        for (int jp = 1; jp < 8; ++jp) {
            float a = yr[jp], b2 = yi[jp];
            yr[jp] = a * wr - b2 * wi;
            yi[jp] = a * wi + b2 * wr;
            float nr = wr * c1 - wi * s1, ni = wr * s1 + wi * c1;
            wr = nr; wi = ni;
        }
#pragma unroll
        for (int j = 0; j < 8; ++j) Z[PD2(t + (j << 10))] = make_float2(yr[j], yi[j]);
    }
    __syncthreads();
    s8f<1024>(Z, t); __syncthreads();
    s8f<128>(Z, t);  __syncthreads();
    s8f<16>(Z, t);   __syncthreads();
    const float2* H = hf + (size_t)d * HFS;
    if (t == 0) {
        // orbit {0, 4096}
        float4 Af = *(const float4*)&Z[0];
        float2 S0 = make_float2(Af.x + Af.z, Af.y + Af.w);
        float2 S4 = make_float2(Af.x - Af.z, Af.y - Af.w);
        float x0 = S0.x + S0.y, xm = S0.x - S0.y;
        float2 H0 = H[0], Hm = H[8192], H4 = H[4096];
        float y0r = x0 * H0.x, y0i = x0 * H0.y;
        float ymr = xm * Hm.x, ymi = xm * Hm.y;
        float yer = 0.5f*(y0r + ymr), yei = 0.5f*(y0i + ymi);
        float yor = 0.5f*(y0r - ymr), yoi = 0.5f*(y0i - ymi);
        float2 spdc = make_float2(yer - yoi, yei + yor);
        float y4r = S4.x * H4.x + S4.y * H4.y;
        float y4i = S4.x * H4.y - S4.y * H4.x;
        float2 sp4 = make_float2(y4r, -y4i);
        Z[0] = make_float2(spdc.x + sp4.x, spdc.y + sp4.y);
        Z[1] = make_float2(spdc.x - sp4.x, spdc.y - sp4.y);
        // orbit {2048, 6144}
        float4 Bf = *(const float4*)&Z[PD2(8)];
        float2 S2k = make_float2(Bf.x + Bf.z, Bf.y + Bf.w);
        float2 S6k = make_float2(Bf.x - Bf.z, Bf.y - Bf.w);
        const float R2 = 0.70710678118654752f;
        float2 spa, spb;
        umr(S2k, S6k, R2, -R2, H[2048], H[6144], spa, spb);
        Z[PD2(8)]     = make_float2(spa.x + spb.x, spa.y + spb.y);
        Z[PD2(8) + 1] = make_float2(spa.x - spb.x, spa.y - spb.y);
    } else {
        orbit_conv(Z, H, t);
    }
    orbit_conv(Z, H, t + 1024);
    __syncthreads();
    s8i<16>(Z, t);   __syncthreads();
    s8i<128>(Z, t);  __syncthreads();
    s8i<1024>(Z, t); __syncthreads();
    // fused final inverse stage (M=8192) + gating epilogue
    float xr[8], xi[8];
#pragma unroll
    for (int j = 0; j < 8; ++j) { float2 z = Z[PD2(t + (j << 10))]; xr[j] = z.x; xi[j] = z.y; }
    {
        float c1, s1;
        __sincosf(ANG8K * (float)t, &s1, &c1);
        float wr = c1, wi = s1;
#pragma unroll
        for (int j = 1; j < 8; ++j) {
            float a = xr[j], b2 = xi[j];
            xr[j] = a * wr - b2 * wi;
            xi[j] = a * wi + b2 * wr;
            float nr = wr * c1 - wi * s1, ni = wr * s1 + wi * c1;
            wr = nr; wi = ni;
        }
    }
    float yr[8], yi[8];
    dft8<1>(xr, xi, yr, yi);
    const float sc = 1.0f / 8192.0f;
    const float w00 = cw0[d * 3], w01 = cw0[d * 3 + 1], w02 = cw0[d * 3 + 2], bi0 = cb0[d];
    const float w10 = cw1[d * 3], w11 = cw1[d * 3 + 1], w12 = cw1[d * 3 + 2], bi1 = cb1[d];
    const unsigned int* R0 = (const unsigned int*)(proj + (size_t)2048 * L_SZ + rowoff);
    const unsigned int* R1 = (const unsigned int*)(proj + (size_t)4096 * L_SZ + rowoff);
    unsigned int* gout = (unsigned int*)gatedT + ((size_t)d * 32768 + b * 4096);
#pragma unroll
    for (int j = 0; j < 4; ++j) {
        const int n = t + (j << 10);
        const float v0 = yr[j] * sc;
        const float v1 = yi[j] * sc;
        unsigned int m0u = (n > 0) ? R0[n - 1] : 0u;
        unsigned int c0u = R0[n];
        unsigned int p0u = (n < 4095) ? R0[n + 1] : 0u;
        unsigned int m1u = (n > 0) ? R1[n - 1] : 0u;
        unsigned int c1u = R1[n];
        unsigned int p1u = (n < 4095) ? R1[n + 1] : 0u;
        float g00 = w00 * hi2f(m0u) + w01 * lo2f(c0u) + w02 * hi2f(c0u) + bi0;
        float g01 = w00 * lo2f(c0u) + w01 * hi2f(c0u) + w02 * lo2f(p0u) + bi0;
        float g10 = w10 * hi2f(m1u) + w11 * lo2f(c1u) + w12 * hi2f(c1u) + bi1;
        float g11 = w10 * lo2f(c1u) + w11 * hi2f(c1u) + w12 * lo2f(p1u) + bi1;
        unsigned int o = (unsigned int)f2bu(v0 * g00 * g10)
                       | ((unsigned int)f2bu(v1 * g01 * g11) << 16);
        gout[n] = o;
    }
}

// ---------------------------------------------------------------------------
// gatedT[256][65536] -> gated[65536][256]  (bf16 transpose, 64x64 tiles)
// ---------------------------------------------------------------------------
__global__ __launch_bounds__(256) void transpose_k(
    const ushort* __restrict__ gatedT, ushort* __restrict__ gated)
{
    __shared__ ushort T2[64 * 66];
    const int tid = threadIdx.x;
    const int m0 = blockIdx.x * 64, d0 = blockIdx.y * 64;
    const int rr = tid >> 3, co = (tid & 7) * 8;
#pragma unroll
    for (int it = 0; it < 2; ++it) {
        const int dr = rr + 32 * it;
        const uint4 val = *(const uint4*)(gatedT + (size_t)(d0 + dr) * 65536 + m0 + co);
        const ushort* vs = (const ushort*)&val;
#pragma unroll
        for (int i = 0; i < 8; ++i)
            T2[(co + i) * 66 + dr] = vs[i];
    }
    __syncthreads();
#pragma unroll
    for (int it = 0; it < 2; ++it) {
        const int mr = rr + 32 * it;
        uint w0 = *(const uint*)(T2 + mr * 66 + co);
        uint w1 = *(const uint*)(T2 + mr * 66 + co + 2);
        uint w2 = *(const uint*)(T2 + mr * 66 + co + 4);
        uint w3 = *(const uint*)(T2 + mr * 66 + co + 6);
        uint4 ov; ov.x = w0; ov.y = w1; ov.z = w2; ov.w = w3;
        *(uint4*)(gated + (size_t)(m0 + mr) * 256 + d0 + co) = ov;
    }
}

// ---------------------------------------------------------------------------
extern "C" void kernel_launch(void* const* d_in, const int* in_sizes, int n_in,
                              void* d_out, int out_size, void* d_ws, size_t ws_size,
                              hipStream_t stream)
{
    const float* x    = (const float*)d_in[0];
    const float* inW  = (const float*)d_in[1];
    const float* inb  = (const float*)d_in[2];
    const float* c0W  = (const float*)d_in[3];
    const float* c0b  = (const float*)d_in[4];
    const float* c1W  = (const float*)d_in[5];
    const float* c1b  = (const float*)d_in[6];
    const float* mW1  = (const float*)d_in[7];
    const float* mb1  = (const float*)d_in[8];
    const float* mW2  = (const float*)d_in[9];
    const float* mb2  = (const float*)d_in[10];
    const float* oW   = (const float*)d_in[11];
    const float* ob   = (const float*)d_in[12];
    const float* tpos = (const float*)d_in[13];
    float* out = (float*)d_out;

    char* ws = (char*)d_ws;
    // NO aliasing — every buffer has its own region (peak 185.2 MB, fits: round-2 used 185.3)
    bf16*   proj   = (bf16*)(ws);                    // 96 MB [3][2048][8192]: v, raw0, raw1
    bf16*   gatedT = (bf16*)(ws + 100663296);        // 32 MB [256][65536]
    bf16*   gated  = (bf16*)(ws + 134217728);        // 32 MB [65536][256]
    float2* hf     = (float2*)(ws + 167772160);      // 16.78 MB [256][HFS]
    float*  h      = (float*)(ws + 184551424);       // 8 MB [256][8192]

    build_h<<<256, 256, 0, stream>>>(tpos, mW1, mb1, mW2, mb2, h);
    fft_filter<<<256, 1024, 0, stream>>>(h, hf);
    gemm_proj<<<3072, 256, 0, stream>>>(x, inW, inb, proj);
    fft_conv<<<2048, 1024, 0, stream>>>(proj, hf, c0W, c0b, c1W, c1b, gatedT);
    transpose_k<<<dim3(1024, 4), 256, 0, stream>>>((const ushort*)gatedT, (ushort*)gated);
    gemm_out_k<<<1024, 256, 0, stream>>>(gated, oW, ob, out);
}